// Round 1
// baseline (3122.119 us; speedup 1.0000x reference)
//
#include <hip/hip_runtime.h>
#include <hip/hip_bf16.h>
#include <cstdint>
#include <cstddef>

#define HD 128

typedef __bf16 bf16x8 __attribute__((ext_vector_type(8)));
typedef float  f32x4  __attribute__((ext_vector_type(4)));

// Swizzled LDS byte offset for element row r, byte-in-row b (row = 256B = 16 chunks of 16B).
// chunk ^= (r&7) spreads the stride-256B column access across banks.
__device__ __forceinline__ int swz(int r, int byteInRow) {
    int chunk = (byteInRow >> 4) ^ (r & 7);
    return r * 256 + (chunk << 4) + (byteInRow & 15);
}

__device__ __forceinline__ float silu_f(float v) {
    return v / (1.f + __expf(-v));
}

// y = x_eff + silu(silu(x_eff@W0+b0)@W1+b1),  x_eff = x * (scale?scale[row]:1)
// wt: bf16, [2][128][128] TRANSPOSED: wt[m][j][k] = W[m][k][j]. bias: f32 [2][128].
__global__ __launch_bounds__(256) void resid_kernel(
    const float* __restrict__ x, const float* __restrict__ scale,
    const __bf16* __restrict__ wt, const float* __restrict__ bias,
    float* __restrict__ y, int nrows)
{
    __shared__ char lds[65536];                 // [0,32768): x bf16 tile, [32768,65536): h bf16 tile
    const int tid  = threadIdx.x;
    const int lane = tid & 63;
    const int wv   = tid >> 6;                  // wave 0..3, owns rows wv*32..wv*32+31
    const int crow = lane & 15;
    const int kgrp = lane >> 4;
    const int r0   = blockIdx.x * 128;

    // ---- stage x (scaled) -> bf16 LDS ----
    {
        const int q = tid & 15;                 // 16B chunk (8 cols)
        #pragma unroll
        for (int rr = 0; rr < 8; ++rr) {
            const int r  = (tid >> 4) + rr * 16;
            const int gr = r0 + r;
            float4 a = {0,0,0,0}, b = {0,0,0,0};
            if (gr < nrows) {
                const float4* p = (const float4*)(x + (size_t)gr * HD + q * 8);
                a = p[0]; b = p[1];
                if (scale) {
                    const float s = scale[gr];
                    a.x*=s; a.y*=s; a.z*=s; a.w*=s;
                    b.x*=s; b.y*=s; b.z*=s; b.w*=s;
                }
            }
            bf16x8 v;
            v[0]=(__bf16)a.x; v[1]=(__bf16)a.y; v[2]=(__bf16)a.z; v[3]=(__bf16)a.w;
            v[4]=(__bf16)b.x; v[5]=(__bf16)b.y; v[6]=(__bf16)b.z; v[7]=(__bf16)b.w;
            *(bf16x8*)(lds + swz(r, q * 16)) = v;
        }
    }
    __syncthreads();

    const int mrow0 = wv * 32;
    f32x4 acc[2][8];

    // ---- matmul 1: h = silu(x@W0 + b0) ----
    #pragma unroll
    for (int m = 0; m < 2; ++m)
        #pragma unroll
        for (int n = 0; n < 8; ++n) {
            const float bv = bias[n * 16 + crow];
            f32x4 t = {bv, bv, bv, bv};
            acc[m][n] = t;
        }
    {
        bf16x8 afr[2][4];
        #pragma unroll
        for (int m = 0; m < 2; ++m)
            #pragma unroll
            for (int kk = 0; kk < 4; ++kk)
                afr[m][kk] = *(const bf16x8*)(lds + swz(mrow0 + m*16 + crow, kk*64 + kgrp*16));
        #pragma unroll
        for (int n = 0; n < 8; ++n) {
            bf16x8 bfr[4];
            #pragma unroll
            for (int kk = 0; kk < 4; ++kk)
                bfr[kk] = *(const bf16x8*)(wt + (size_t)(n*16 + crow)*HD + kk*32 + kgrp*8);
            #pragma unroll
            for (int m = 0; m < 2; ++m)
                #pragma unroll
                for (int kk = 0; kk < 4; ++kk)
                    acc[m][n] = __builtin_amdgcn_mfma_f32_16x16x32_bf16(afr[m][kk], bfr[kk], acc[m][n], 0, 0, 0);
        }
    }
    #pragma unroll
    for (int m = 0; m < 2; ++m)
        #pragma unroll
        for (int n = 0; n < 8; ++n)
            #pragma unroll
            for (int rg = 0; rg < 4; ++rg) {
                const float h = silu_f(acc[m][n][rg]);
                const int rr = mrow0 + m*16 + kgrp*4 + rg;   // D: row=(lane>>4)*4+reg
                const int cc = n*16 + crow;                   // D: col=lane&15
                *(__bf16*)(lds + 32768 + swz(rr, cc*2)) = (__bf16)h;
            }
    __syncthreads();

    // ---- matmul 2: y = x_eff + silu(h@W1 + b1) ----
    #pragma unroll
    for (int m = 0; m < 2; ++m)
        #pragma unroll
        for (int n = 0; n < 8; ++n) {
            const float bv = bias[HD + n * 16 + crow];
            f32x4 t = {bv, bv, bv, bv};
            acc[m][n] = t;
        }
    {
        bf16x8 afr[2][4];
        #pragma unroll
        for (int m = 0; m < 2; ++m)
            #pragma unroll
            for (int kk = 0; kk < 4; ++kk)
                afr[m][kk] = *(const bf16x8*)(lds + 32768 + swz(mrow0 + m*16 + crow, kk*64 + kgrp*16));
        #pragma unroll
        for (int n = 0; n < 8; ++n) {
            bf16x8 bfr[4];
            #pragma unroll
            for (int kk = 0; kk < 4; ++kk)
                bfr[kk] = *(const bf16x8*)(wt + 16384 + (size_t)(n*16 + crow)*HD + kk*32 + kgrp*8);
            #pragma unroll
            for (int m = 0; m < 2; ++m)
                #pragma unroll
                for (int kk = 0; kk < 4; ++kk)
                    acc[m][n] = __builtin_amdgcn_mfma_f32_16x16x32_bf16(afr[m][kk], bfr[kk], acc[m][n], 0, 0, 0);
        }
    }
    #pragma unroll
    for (int m = 0; m < 2; ++m)
        #pragma unroll
        for (int n = 0; n < 8; ++n)
            #pragma unroll
            for (int rg = 0; rg < 4; ++rg) {
                const int rr = mrow0 + m*16 + kgrp*4 + rg;
                const int gr = r0 + rr;
                if (gr < nrows) {
                    const int cc = n*16 + crow;
                    const float h = silu_f(acc[m][n][rg]);
                    float xe = x[(size_t)gr*HD + cc];
                    if (scale) xe *= scale[gr];
                    y[(size_t)gr*HD + cc] = xe + h;
                }
            }
}

// conv[row] += (s_dst[col] * (ef@e_lin) * conv_smooth)   -- one edge per 128 threads
__global__ __launch_bounds__(256) void edge_kernel(
    const float* __restrict__ ef, const float* __restrict__ elin,
    const float* __restrict__ cs, const int* __restrict__ erow, const int* __restrict__ ecol,
    const float* __restrict__ sdst, float* __restrict__ conv, int nedges)
{
    const int e = blockIdx.x * 2 + (threadIdx.x >> 7);
    if (e >= nedges) return;
    const int j = threadIdx.x & 127;
    const float4* efp = (const float4*)(ef + (size_t)e * 16);
    float ev[16];
    *(float4*)&ev[0]  = efp[0];
    *(float4*)&ev[4]  = efp[1];
    *(float4*)&ev[8]  = efp[2];
    *(float4*)&ev[12] = efp[3];
    float f = 0.f;
    #pragma unroll
    for (int k = 0; k < 16; ++k) f += ev[k] * elin[k * HD + j];
    f *= cs[e];
    const int c = ecol[e];
    const int r = erow[e];
    const float v = sdst[(size_t)c * HD + j] * f;
    atomicAdd(conv + (size_t)r * HD + j, v);
}

__global__ __launch_bounds__(256) void ew_mul_kernel(float* __restrict__ d, const float* __restrict__ s, int n4) {
    int i = blockIdx.x * blockDim.x + threadIdx.x;
    const int stride = gridDim.x * blockDim.x;
    for (; i < n4; i += stride) {
        float4 a = ((const float4*)d)[i];
        const float4 b = ((const float4*)s)[i];
        a.x*=b.x; a.y*=b.y; a.z*=b.z; a.w*=b.w;
        ((float4*)d)[i] = a;
    }
}

__global__ __launch_bounds__(256) void ew_add_kernel(float* __restrict__ o, const float* __restrict__ a,
                                                     const float* __restrict__ b, int n4) {
    int i = blockIdx.x * blockDim.x + threadIdx.x;
    const int stride = gridDim.x * blockDim.x;
    for (; i < n4; i += stride) {
        const float4 x = ((const float4*)a)[i];
        const float4 y = ((const float4*)b)[i];
        float4 r;
        r.x = x.x + y.x; r.y = x.y + y.y; r.z = x.z + y.z; r.w = x.w + y.w;
        ((float4*)o)[i] = r;
    }
}

// sorted segment-sum pooling: block handles 512 contiguous nodes, flush on graph change
__global__ __launch_bounds__(128) void pool_kernel(
    const float* __restrict__ s, const int* __restrict__ bidx,
    float* __restrict__ g, int n)
{
    const int j = threadIdx.x;
    int i = blockIdx.x * 512;
    if (i >= n) return;
    const int end = (i + 512 < n) ? (i + 512) : n;
    float acc = 0.f;
    int cur = bidx[i];
    for (; i < end; ++i) {
        const int b = bidx[i];
        if (b != cur) { atomicAdd(g + (size_t)cur * HD + j, acc); acc = 0.f; cur = b; }
        acc += s[(size_t)i * HD + j];
    }
    atomicAdd(g + (size_t)cur * HD + j, acc);
}

// wt[mat][j][k] = (bf16) W[mat][k][j]
__global__ __launch_bounds__(256) void convw_kernel(const float* __restrict__ W, __bf16* __restrict__ wt, int total) {
    const int idx = blockIdx.x * 256 + threadIdx.x;
    if (idx >= total) return;
    const int mat = idx >> 14;
    const int rem = idx & 16383;
    const int jj = rem >> 7, kk = rem & 127;
    wt[idx] = (__bf16)W[(size_t)mat * 16384 + kk * HD + jj];
}

extern "C" void kernel_launch(void* const* d_in, const int* in_sizes, int n_in,
                              void* d_out, int out_size, void* d_ws, size_t ws_size,
                              hipStream_t stream) {
    const float* scalar = (const float*)d_in[0];
    const float* ef     = (const float*)d_in[1];
    const int*   eidx   = (const int*)  d_in[2];
    const float* Cn     = (const float*)d_in[3];
    const float* cs     = (const float*)d_in[4];
    const int*   bidx   = (const int*)  d_in[5];
    const float* resW   = (const float*)d_in[6];
    const float* resB   = (const float*)d_in[7];
    const float* elin   = (const float*)d_in[8];

    const int N      = in_sizes[0] / HD;
    const int E      = in_sizes[1] / 16;
    const int n_res  = in_sizes[7] / (2 * HD);
    const int layers = (n_res - 3) / 6;
    const int G      = out_size / HD;
    const size_t nfeat = (size_t)N * HD;

    char* p = (char*)d_ws;
    float* A   = (float*)p; p += nfeat * 4;
    float* Bs  = (float*)p; p += nfeat * 4;          // s_src
    float* Cs  = (float*)p; p += nfeat * 4;          // s_dst
    float* Dc  = (float*)p; p += nfeat * 4;          // conv / chain buffer
    __bf16* wt = (__bf16*)p; p += (size_t)n_res * 2 * 16384 * 2;
    float* graph = (float*)p; p += (size_t)G * HD * 4;

    const int totW = n_res * 2 * 16384;
    convw_kernel<<<(totW + 255) / 256, 256, 0, stream>>>(resW, wt, totW);

    const int gridR = (N + 127) / 128;
    const int n4 = (int)(nfeat / 4);
    const float* cur = scalar;
    for (int i = 0; i < layers; ++i) {
        const int pb = 6 * i;
        resid_kernel<<<gridR, 256, 0, stream>>>(cur, nullptr, wt + (size_t)pb * 32768, resB + (size_t)pb * 256, Bs, N);
        resid_kernel<<<gridR, 256, 0, stream>>>(cur, nullptr, wt + (size_t)(pb + 1) * 32768, resB + (size_t)(pb + 1) * 256, Cs, N);
        hipMemsetAsync(Dc, 0, nfeat * 4, stream);
        edge_kernel<<<(E + 1) / 2, 256, 0, stream>>>(ef, elin + (size_t)i * 16 * HD, cs, eidx, eidx + E, Cs, Dc, E);
        resid_kernel<<<gridR, 256, 0, stream>>>(Dc, Cn, wt + (size_t)(pb + 2) * 32768, resB + (size_t)(pb + 2) * 256, Dc, N);
        resid_kernel<<<gridR, 256, 0, stream>>>(Dc, nullptr, wt + (size_t)(pb + 3) * 32768, resB + (size_t)(pb + 3) * 256, Dc, N);
        ew_mul_kernel<<<2048, 256, 0, stream>>>(Dc, Bs, n4);
        resid_kernel<<<gridR, 256, 0, stream>>>(Dc, nullptr, wt + (size_t)(pb + 4) * 32768, resB + (size_t)(pb + 4) * 256, Dc, N);
        resid_kernel<<<gridR, 256, 0, stream>>>(Dc, nullptr, wt + (size_t)(pb + 5) * 32768, resB + (size_t)(pb + 5) * 256, Dc, N);
        ew_add_kernel<<<2048, 256, 0, stream>>>(A, cur, Dc, n4);
        cur = A;
    }

    hipMemsetAsync(graph, 0, (size_t)G * HD * 4, stream);
    pool_kernel<<<(N + 511) / 512, 128, 0, stream>>>(cur, bidx, graph, N);

    const int q = 6 * layers;
    const int gridG = (G + 127) / 128;
    resid_kernel<<<gridG, 256, 0, stream>>>(graph, nullptr, wt + (size_t)q * 32768, resB + (size_t)q * 256, graph, G);
    resid_kernel<<<gridG, 256, 0, stream>>>(graph, nullptr, wt + (size_t)(q + 1) * 32768, resB + (size_t)(q + 1) * 256, graph, G);
    resid_kernel<<<gridG, 256, 0, stream>>>(graph, nullptr, wt + (size_t)(q + 2) * 32768, resB + (size_t)(q + 2) * 256, (float*)d_out, G);
}

// Round 2
// 2390.738 us; speedup vs baseline: 1.3059x; 1.3059x over previous
//
#include <hip/hip_runtime.h>
#include <hip/hip_bf16.h>
#include <cstdint>
#include <cstddef>

#define HD 128

typedef __bf16 bf16x8 __attribute__((ext_vector_type(8)));
typedef float  f32x4  __attribute__((ext_vector_type(4)));

// Swizzled LDS byte offset for element row r, byte-in-row b (row = 256B = 16 chunks of 16B).
// chunk ^= (r&7) spreads the stride-256B column access across banks.
__device__ __forceinline__ int swz(int r, int byteInRow) {
    int chunk = (byteInRow >> 4) ^ (r & 7);
    return r * 256 + (chunk << 4) + (byteInRow & 15);
}

__device__ __forceinline__ float silu_f(float v) {
    return v / (1.f + __expf(-v));
}

// ---- shared building blocks for the residual-MLP kernels ----

// stage 128x128 f32 tile (optionally elementwise-multiplied by premul) as bf16 into lds[0..32768)
__device__ __forceinline__ void stage_x(const float* __restrict__ x, const float* __restrict__ premul,
                                        char* lds, int r0, int nrows, int tid) {
    const int q = tid & 15;
    #pragma unroll
    for (int rr = 0; rr < 8; ++rr) {
        const int r  = (tid >> 4) + rr * 16;
        const int gr = r0 + r;
        float4 a = {0,0,0,0}, b = {0,0,0,0};
        if (gr < nrows) {
            const float4* p = (const float4*)(x + (size_t)gr * HD + q * 8);
            a = p[0]; b = p[1];
            if (premul) {
                const float4* pm = (const float4*)(premul + (size_t)gr * HD + q * 8);
                const float4 m0 = pm[0], m1 = pm[1];
                a.x*=m0.x; a.y*=m0.y; a.z*=m0.z; a.w*=m0.w;
                b.x*=m1.x; b.y*=m1.y; b.z*=m1.z; b.w*=m1.w;
            }
        }
        bf16x8 v;
        v[0]=(__bf16)a.x; v[1]=(__bf16)a.y; v[2]=(__bf16)a.z; v[3]=(__bf16)a.w;
        v[4]=(__bf16)b.x; v[5]=(__bf16)b.y; v[6]=(__bf16)b.z; v[7]=(__bf16)b.w;
        *(bf16x8*)(lds + swz(r, q * 16)) = v;
    }
}

// acc[2][8] = (LDS tile @ W) + bias ; A-frags from lds+src_off, W (transposed bf16) from global
__device__ __forceinline__ void mm_pass(const char* lds, int src_off,
                                        const __bf16* __restrict__ wt, const float* __restrict__ bias,
                                        int mrow0, int crow, int kgrp, f32x4 acc[2][8]) {
    bf16x8 afr[2][4];
    #pragma unroll
    for (int m = 0; m < 2; ++m)
        #pragma unroll
        for (int kk = 0; kk < 4; ++kk)
            afr[m][kk] = *(const bf16x8*)(lds + src_off + swz(mrow0 + m*16 + crow, kk*64 + kgrp*16));
    #pragma unroll
    for (int n = 0; n < 8; ++n) {
        const float bv = bias[n * 16 + crow];
        #pragma unroll
        for (int m = 0; m < 2; ++m) { f32x4 t = {bv, bv, bv, bv}; acc[m][n] = t; }
    }
    #pragma unroll
    for (int n = 0; n < 8; ++n) {
        bf16x8 bfr[4];
        #pragma unroll
        for (int kk = 0; kk < 4; ++kk)
            bfr[kk] = *(const bf16x8*)(wt + (size_t)(n*16 + crow)*HD + kk*32 + kgrp*8);
        #pragma unroll
        for (int m = 0; m < 2; ++m)
            #pragma unroll
            for (int kk = 0; kk < 4; ++kk)
                acc[m][n] = __builtin_amdgcn_mfma_f32_16x16x32_bf16(afr[m][kk], bfr[kk], acc[m][n], 0, 0, 0);
    }
}

// silu(acc) -> bf16 h-tile at lds+dst_off
__device__ __forceinline__ void write_h(char* lds, int dst_off, const f32x4 acc[2][8],
                                        int mrow0, int crow, int kgrp) {
    #pragma unroll
    for (int m = 0; m < 2; ++m)
        #pragma unroll
        for (int n = 0; n < 8; ++n)
            #pragma unroll
            for (int rg = 0; rg < 4; ++rg)
                *(__bf16*)(lds + dst_off + swz(mrow0 + m*16 + kgrp*4 + rg, (n*16 + crow)*2)) =
                    (__bf16)silu_f(acc[m][n][rg]);
}

// ---- dual residual: out1 = x + mlp0(x), out2 = x + mlp1(x) (shared staging) ----
__global__ __launch_bounds__(256) void resid_dual_kernel(
    const float* __restrict__ x,
    const __bf16* __restrict__ wtA, const float* __restrict__ bA,
    const __bf16* __restrict__ wtB, const float* __restrict__ bB,
    float* __restrict__ out1, float* __restrict__ out2, int nrows)
{
    __shared__ char lds[65536];
    const int tid = threadIdx.x, lane = tid & 63, wv = tid >> 6;
    const int crow = lane & 15, kgrp = lane >> 4;
    const int r0 = blockIdx.x * 128, mrow0 = wv * 32;

    stage_x(x, nullptr, lds, r0, nrows, tid);
    __syncthreads();

    f32x4 acc[2][8];
    f32x4 xe[2][8];
    // pass A
    mm_pass(lds, 0, wtA, bA, mrow0, crow, kgrp, acc);
    write_h(lds, 32768, acc, mrow0, crow, kgrp);
    __syncthreads();
    mm_pass(lds, 32768, wtA + 16384, bA + HD, mrow0, crow, kgrp, acc);
    #pragma unroll
    for (int m = 0; m < 2; ++m)
        #pragma unroll
        for (int n = 0; n < 8; ++n)
            #pragma unroll
            for (int rg = 0; rg < 4; ++rg) {
                const int gr = r0 + mrow0 + m*16 + kgrp*4 + rg;
                const int cc = n*16 + crow;
                float xv = 0.f;
                if (gr < nrows) xv = x[(size_t)gr*HD + cc];
                xe[m][n][rg] = xv;
                if (gr < nrows) out1[(size_t)gr*HD + cc] = xv + silu_f(acc[m][n][rg]);
            }
    __syncthreads();
    // pass B (xbuf still holds x)
    mm_pass(lds, 0, wtB, bB, mrow0, crow, kgrp, acc);
    write_h(lds, 32768, acc, mrow0, crow, kgrp);
    __syncthreads();
    mm_pass(lds, 32768, wtB + 16384, bB + HD, mrow0, crow, kgrp, acc);
    #pragma unroll
    for (int m = 0; m < 2; ++m)
        #pragma unroll
        for (int n = 0; n < 8; ++n)
            #pragma unroll
            for (int rg = 0; rg < 4; ++rg) {
                const int gr = r0 + mrow0 + m*16 + kgrp*4 + rg;
                if (gr < nrows) {
                    const int cc = n*16 + crow;
                    out2[(size_t)gr*HD + cc] = xe[m][n][rg] + silu_f(acc[m][n][rg]);
                }
            }
}

// ---- chained double residual with optional elementwise premul / postadd ----
// y = postadd + R2(R1(premul*x))   where R(v) = v + mlp(v)
__global__ __launch_bounds__(256) void resid_chain2_kernel(
    const float* __restrict__ x, const float* __restrict__ premul,
    const __bf16* __restrict__ wt01, const float* __restrict__ b01,
    const __bf16* __restrict__ wt23, const float* __restrict__ b23,
    const float* __restrict__ postadd, float* __restrict__ y, int nrows)
{
    __shared__ char lds[65536];
    const int tid = threadIdx.x, lane = tid & 63, wv = tid >> 6;
    const int crow = lane & 15, kgrp = lane >> 4;
    const int r0 = blockIdx.x * 128, mrow0 = wv * 32;

    stage_x(x, premul, lds, r0, nrows, tid);
    __syncthreads();

    f32x4 acc[2][8];
    f32x4 y1[2][8];
    mm_pass(lds, 0, wt01, b01, mrow0, crow, kgrp, acc);
    write_h(lds, 32768, acc, mrow0, crow, kgrp);
    __syncthreads();
    mm_pass(lds, 32768, wt01 + 16384, b01 + HD, mrow0, crow, kgrp, acc);
    #pragma unroll
    for (int m = 0; m < 2; ++m)
        #pragma unroll
        for (int n = 0; n < 8; ++n)
            #pragma unroll
            for (int rg = 0; rg < 4; ++rg) {
                const int gr = r0 + mrow0 + m*16 + kgrp*4 + rg;
                const int cc = n*16 + crow;
                float xv = 0.f;
                if (gr < nrows) {
                    xv = x[(size_t)gr*HD + cc];
                    if (premul) xv *= premul[(size_t)gr*HD + cc];
                }
                y1[m][n][rg] = xv + silu_f(acc[m][n][rg]);
            }
    // xbuf reads all completed before previous barrier -> safe to overwrite
    #pragma unroll
    for (int m = 0; m < 2; ++m)
        #pragma unroll
        for (int n = 0; n < 8; ++n)
            #pragma unroll
            for (int rg = 0; rg < 4; ++rg)
                *(__bf16*)(lds + swz(mrow0 + m*16 + kgrp*4 + rg, (n*16 + crow)*2)) =
                    (__bf16)y1[m][n][rg];
    __syncthreads();
    mm_pass(lds, 0, wt23, b23, mrow0, crow, kgrp, acc);
    write_h(lds, 32768, acc, mrow0, crow, kgrp);
    __syncthreads();
    mm_pass(lds, 32768, wt23 + 16384, b23 + HD, mrow0, crow, kgrp, acc);
    #pragma unroll
    for (int m = 0; m < 2; ++m)
        #pragma unroll
        for (int n = 0; n < 8; ++n)
            #pragma unroll
            for (int rg = 0; rg < 4; ++rg) {
                const int gr = r0 + mrow0 + m*16 + kgrp*4 + rg;
                if (gr < nrows) {
                    const int cc = n*16 + crow;
                    float v = y1[m][n][rg] + silu_f(acc[m][n][rg]);
                    if (postadd) v += postadd[(size_t)gr*HD + cc];
                    y[(size_t)gr*HD + cc] = v;
                }
            }
}

// ---- single residual (graph-level, tiny) ----
__global__ __launch_bounds__(256) void resid_kernel(
    const float* __restrict__ x, const __bf16* __restrict__ wt, const float* __restrict__ bias,
    float* __restrict__ y, int nrows)
{
    __shared__ char lds[65536];
    const int tid = threadIdx.x, lane = tid & 63, wv = tid >> 6;
    const int crow = lane & 15, kgrp = lane >> 4;
    const int r0 = blockIdx.x * 128, mrow0 = wv * 32;

    stage_x(x, nullptr, lds, r0, nrows, tid);
    __syncthreads();
    f32x4 acc[2][8];
    mm_pass(lds, 0, wt, bias, mrow0, crow, kgrp, acc);
    write_h(lds, 32768, acc, mrow0, crow, kgrp);
    __syncthreads();
    mm_pass(lds, 32768, wt + 16384, bias + HD, mrow0, crow, kgrp, acc);
    #pragma unroll
    for (int m = 0; m < 2; ++m)
        #pragma unroll
        for (int n = 0; n < 8; ++n)
            #pragma unroll
            for (int rg = 0; rg < 4; ++rg) {
                const int gr = r0 + mrow0 + m*16 + kgrp*4 + rg;
                if (gr < nrows) {
                    const int cc = n*16 + crow;
                    y[(size_t)gr*HD + cc] = x[(size_t)gr*HD + cc] + silu_f(acc[m][n][rg]);
                }
            }
}

// ---- CSR build: histogram -> scan -> scatter ----
__global__ __launch_bounds__(256) void hist_kernel(const int* __restrict__ erow, int* __restrict__ cnt, int E) {
    int i = blockIdx.x * blockDim.x + threadIdx.x;
    const int stride = gridDim.x * blockDim.x;
    for (; i < E; i += stride) atomicAdd(&cnt[erow[i]], 1);
}

__global__ __launch_bounds__(256) void scan1_kernel(const int* __restrict__ cnt, int* __restrict__ part, int n) {
    __shared__ int red[256];
    const int base = blockIdx.x * 1024;
    int s = 0;
    for (int i = threadIdx.x; i < 1024; i += 256) {
        const int idx = base + i;
        s += (idx < n) ? cnt[idx] : 0;
    }
    red[threadIdx.x] = s; __syncthreads();
    for (int o = 128; o > 0; o >>= 1) {
        if (threadIdx.x < o) red[threadIdx.x] += red[threadIdx.x + o];
        __syncthreads();
    }
    if (threadIdx.x == 0) part[blockIdx.x] = red[0];
}

__global__ void scan2_kernel(int* __restrict__ part, int nb, int* __restrict__ rowptr, int n) {
    if (threadIdx.x == 0 && blockIdx.x == 0) {
        int run = 0;
        for (int b = 0; b < nb; ++b) { const int v = part[b]; part[b] = run; run += v; }
        rowptr[n] = run;
    }
}

__global__ __launch_bounds__(256) void scan3_kernel(const int* __restrict__ cnt, const int* __restrict__ part,
                                                    int* __restrict__ rowptr, int n) {
    __shared__ int sc[257];
    const int base = blockIdx.x * 1024;
    const int i0 = base + threadIdx.x * 4;
    int v[4]; int s = 0;
    #pragma unroll
    for (int q = 0; q < 4; ++q) {
        const int idx = i0 + q;
        v[q] = (idx < n) ? cnt[idx] : 0;
        s += v[q];
    }
    sc[threadIdx.x + 1] = s; __syncthreads();
    if (threadIdx.x == 0) {
        int run = 0;
        for (int i = 0; i < 256; ++i) { const int t = sc[i + 1]; sc[i + 1] = run; run += t; }
    }
    __syncthreads();
    int off = part[blockIdx.x] + sc[threadIdx.x + 1];
    #pragma unroll
    for (int q = 0; q < 4; ++q) {
        const int idx = i0 + q;
        if (idx < n) rowptr[idx] = off;
        off += v[q];
    }
}

__global__ __launch_bounds__(256) void scatter_kernel(const int* __restrict__ erow, const int* __restrict__ rowptr,
                                                      int* __restrict__ cursor, int* __restrict__ eperm, int E) {
    int i = blockIdx.x * blockDim.x + threadIdx.x;
    const int stride = gridDim.x * blockDim.x;
    for (; i < E; i += stride) {
        const int r = erow[i];
        const int p = rowptr[r] + atomicAdd(&cursor[r], 1);
        eperm[p] = i;
    }
}

// ---- CSR gather-reduce conv: conv[v] = Cn[v] * sum_e sdst[col_e] * (ef[e]@elin)*cs[e] ----
__global__ __launch_bounds__(128) void conv_kernel(
    const float* __restrict__ ef, const float* __restrict__ elin,
    const float* __restrict__ cs, const int* __restrict__ ecol,
    const int* __restrict__ rowptr, const int* __restrict__ eperm,
    const float* __restrict__ sdst, const float* __restrict__ Cn,
    float* __restrict__ conv, int nnodes)
{
    const int v = blockIdx.x;
    const int j = threadIdx.x;
    float w[16];
    #pragma unroll
    for (int k = 0; k < 16; ++k) w[k] = elin[k * HD + j];
    const int beg = rowptr[v], end = rowptr[v + 1];
    float acc = 0.f;
    for (int t = beg; t < end; ++t) {
        const int e = __builtin_amdgcn_readfirstlane(eperm[t]);
        const float4* ep = (const float4*)(ef + (size_t)e * 16);
        const float4 e0 = ep[0], e1 = ep[1], e2 = ep[2], e3 = ep[3];
        float f = e0.x*w[0] + e0.y*w[1] + e0.z*w[2] + e0.w*w[3]
                + e1.x*w[4] + e1.y*w[5] + e1.z*w[6] + e1.w*w[7]
                + e2.x*w[8] + e2.y*w[9] + e2.z*w[10] + e2.w*w[11]
                + e3.x*w[12] + e3.y*w[13] + e3.z*w[14] + e3.w*w[15];
        f *= cs[e];
        const int c = __builtin_amdgcn_readfirstlane(ecol[e]);
        acc += sdst[(size_t)c * HD + j] * f;
    }
    conv[(size_t)v * HD + j] = acc * Cn[v];
}

// sorted segment-sum pooling
__global__ __launch_bounds__(128) void pool_kernel(
    const float* __restrict__ s, const int* __restrict__ bidx,
    float* __restrict__ g, int n)
{
    const int j = threadIdx.x;
    int i = blockIdx.x * 512;
    if (i >= n) return;
    const int end = (i + 512 < n) ? (i + 512) : n;
    float acc = 0.f;
    int cur = bidx[i];
    for (; i < end; ++i) {
        const int b = bidx[i];
        if (b != cur) { atomicAdd(g + (size_t)cur * HD + j, acc); acc = 0.f; cur = b; }
        acc += s[(size_t)i * HD + j];
    }
    atomicAdd(g + (size_t)cur * HD + j, acc);
}

// wt[mat][j][k] = (bf16) W[mat][k][j]
__global__ __launch_bounds__(256) void convw_kernel(const float* __restrict__ W, __bf16* __restrict__ wt, int total) {
    const int idx = blockIdx.x * 256 + threadIdx.x;
    if (idx >= total) return;
    const int mat = idx >> 14;
    const int rem = idx & 16383;
    const int jj = rem >> 7, kk = rem & 127;
    wt[idx] = (__bf16)W[(size_t)mat * 16384 + kk * HD + jj];
}

extern "C" void kernel_launch(void* const* d_in, const int* in_sizes, int n_in,
                              void* d_out, int out_size, void* d_ws, size_t ws_size,
                              hipStream_t stream) {
    const float* scalar = (const float*)d_in[0];
    const float* ef     = (const float*)d_in[1];
    const int*   eidx   = (const int*)  d_in[2];
    const float* Cn     = (const float*)d_in[3];
    const float* cs     = (const float*)d_in[4];
    const int*   bidx   = (const int*)  d_in[5];
    const float* resW   = (const float*)d_in[6];
    const float* resB   = (const float*)d_in[7];
    const float* elin   = (const float*)d_in[8];

    const int N      = in_sizes[0] / HD;
    const int E      = in_sizes[1] / 16;
    const int n_res  = in_sizes[7] / (2 * HD);
    const int layers = (n_res - 3) / 6;
    const int G      = out_size / HD;
    const size_t nfeat = (size_t)N * HD;

    char* p = (char*)d_ws;
    float* A   = (float*)p; p += nfeat * 4;
    float* Bs  = (float*)p; p += nfeat * 4;          // s_src
    float* Cs  = (float*)p; p += nfeat * 4;          // s_dst
    float* Dc  = (float*)p; p += nfeat * 4;          // conv / chain buffer
    __bf16* wt = (__bf16*)p; p += (size_t)n_res * 2 * 16384 * 2;
    float* graph = (float*)p; p += (size_t)G * HD * 4;
    int* rowptr = (int*)p;  p += (size_t)(N + 1) * 4;
    int* rowcnt = (int*)p;  p += (size_t)N * 4;
    int* eperm  = (int*)p;  p += (size_t)E * 4;
    int* part   = (int*)p;  p += 256 * 4;

    const int* erow = eidx;
    const int* ecol = eidx + E;

    // weight transpose + bf16 convert
    const int totW = n_res * 2 * 16384;
    convw_kernel<<<(totW + 255) / 256, 256, 0, stream>>>(resW, wt, totW);

    // CSR build (layer-independent, once per call)
    const int nchunks = (N + 1023) / 1024;
    hipMemsetAsync(rowcnt, 0, (size_t)N * 4, stream);
    hist_kernel<<<1024, 256, 0, stream>>>(erow, rowcnt, E);
    scan1_kernel<<<nchunks, 256, 0, stream>>>(rowcnt, part, N);
    scan2_kernel<<<1, 64, 0, stream>>>(part, nchunks, rowptr, N);
    scan3_kernel<<<nchunks, 256, 0, stream>>>(rowcnt, part, rowptr, N);
    hipMemsetAsync(rowcnt, 0, (size_t)N * 4, stream);
    scatter_kernel<<<1024, 256, 0, stream>>>(erow, rowptr, rowcnt, eperm, E);

    const int gridR = (N + 127) / 128;
    const float* cur = scalar;
    for (int i = 0; i < layers; ++i) {
        const int pb = 6 * i;
        resid_dual_kernel<<<gridR, 256, 0, stream>>>(
            cur, wt + (size_t)pb * 32768, resB + (size_t)pb * 256,
            wt + (size_t)(pb + 1) * 32768, resB + (size_t)(pb + 1) * 256, Bs, Cs, N);
        conv_kernel<<<N, 128, 0, stream>>>(
            ef, elin + (size_t)i * 16 * HD, cs, ecol, rowptr, eperm, Cs, Cn, Dc, N);
        resid_chain2_kernel<<<gridR, 256, 0, stream>>>(
            Dc, nullptr,
            wt + (size_t)(pb + 2) * 32768, resB + (size_t)(pb + 2) * 256,
            wt + (size_t)(pb + 3) * 32768, resB + (size_t)(pb + 3) * 256,
            nullptr, Dc, N);
        resid_chain2_kernel<<<gridR, 256, 0, stream>>>(
            Dc, Bs,
            wt + (size_t)(pb + 4) * 32768, resB + (size_t)(pb + 4) * 256,
            wt + (size_t)(pb + 5) * 32768, resB + (size_t)(pb + 5) * 256,
            cur, A, N);
        cur = A;
    }

    hipMemsetAsync(graph, 0, (size_t)G * HD * 4, stream);
    pool_kernel<<<(N + 511) / 512, 128, 0, stream>>>(cur, bidx, graph, N);

    const int q = 6 * layers;
    const int gridG = (G + 127) / 128;
    resid_kernel<<<gridG, 256, 0, stream>>>(graph, wt + (size_t)q * 32768, resB + (size_t)q * 256, graph, G);
    resid_kernel<<<gridG, 256, 0, stream>>>(graph, wt + (size_t)(q + 1) * 32768, resB + (size_t)(q + 1) * 256, graph, G);
    resid_kernel<<<gridG, 256, 0, stream>>>(graph, wt + (size_t)(q + 2) * 32768, resB + (size_t)(q + 2) * 256, (float*)d_out, G);
}

// Round 3
// 1851.139 us; speedup vs baseline: 1.6866x; 1.2915x over previous
//
#include <hip/hip_runtime.h>
#include <hip/hip_bf16.h>
#include <cstdint>
#include <cstddef>

#define HD 128

typedef __bf16 bf16x8 __attribute__((ext_vector_type(8)));
typedef float  f32x4  __attribute__((ext_vector_type(4)));

// Swizzled LDS byte offset: row r (256B rows), byte-in-row b. chunk ^= (r&7) kills
// the stride-256B bank conflict on column-slice ds_read_b128.
__device__ __forceinline__ int swz(int r, int byteInRow) {
    int chunk = (byteInRow >> 4) ^ (r & 7);
    return r * 256 + (chunk << 4) + (byteInRow & 15);
}

__device__ __forceinline__ float silu_f(float v) { return v / (1.f + __expf(-v)); }

// ---- tile-64 residual building blocks (LDS: [0,16384) input bf16, [16384,32768) hidden bf16) ----

__device__ __forceinline__ void stage_x64(const float* __restrict__ x, char* lds,
                                          int r0, int nrows, int tid) {
    const int q = tid & 15;
    #pragma unroll
    for (int rr = 0; rr < 4; ++rr) {
        const int r  = (tid >> 4) + rr * 16;
        const int gr = r0 + r;
        float4 a = {0,0,0,0}, b = {0,0,0,0};
        if (gr < nrows) {
            const float4* p = (const float4*)(x + (size_t)gr * HD + q * 8);
            a = p[0]; b = p[1];
        }
        bf16x8 v;
        v[0]=(__bf16)a.x; v[1]=(__bf16)a.y; v[2]=(__bf16)a.z; v[3]=(__bf16)a.w;
        v[4]=(__bf16)b.x; v[5]=(__bf16)b.y; v[6]=(__bf16)b.z; v[7]=(__bf16)b.w;
        *(bf16x8*)(lds + swz(r, q * 16)) = v;
    }
}

__device__ __forceinline__ void mm_pass64(const char* lds, int off,
                                          const __bf16* __restrict__ wt, const float* __restrict__ bias,
                                          int mrow0, int crow, int kgrp, f32x4 acc[8]) {
    bf16x8 afr[4];
    #pragma unroll
    for (int kk = 0; kk < 4; ++kk)
        afr[kk] = *(const bf16x8*)(lds + off + swz(mrow0 + crow, kk*64 + kgrp*16));
    #pragma unroll
    for (int n = 0; n < 8; ++n) {
        const float bv = bias[n * 16 + crow];
        f32x4 t = {bv, bv, bv, bv};
        acc[n] = t;
    }
    #pragma unroll
    for (int n = 0; n < 8; ++n) {
        bf16x8 bfr[4];
        #pragma unroll
        for (int kk = 0; kk < 4; ++kk)
            bfr[kk] = *(const bf16x8*)(wt + (size_t)(n*16 + crow)*HD + kk*32 + kgrp*8);
        #pragma unroll
        for (int kk = 0; kk < 4; ++kk)
            acc[n] = __builtin_amdgcn_mfma_f32_16x16x32_bf16(afr[kk], bfr[kk], acc[n], 0, 0, 0);
    }
}

__device__ __forceinline__ void write_h64(char* lds, int off, const f32x4 acc[8],
                                          int mrow0, int crow, int kgrp) {
    #pragma unroll
    for (int n = 0; n < 8; ++n)
        #pragma unroll
        for (int rg = 0; rg < 4; ++rg)
            *(__bf16*)(lds + off + swz(mrow0 + kgrp*4 + rg, (n*16 + crow)*2)) =
                (__bf16)silu_f(acc[n][rg]);
}

__device__ __forceinline__ void restage64(char* lds, const f32x4 carry[8],
                                          int mrow0, int crow, int kgrp) {
    #pragma unroll
    for (int n = 0; n < 8; ++n)
        #pragma unroll
        for (int rg = 0; rg < 4; ++rg)
            *(__bf16*)(lds + swz(mrow0 + kgrp*4 + rg, (n*16 + crow)*2)) =
                (__bf16)carry[n][rg];
}

// carry += silu(mlp(region0))
__device__ __forceinline__ void sub_block(char* lds, const __bf16* __restrict__ wt,
                                          const float* __restrict__ bias,
                                          int mrow0, int crow, int kgrp, f32x4 carry[8]) {
    f32x4 acc[8];
    mm_pass64(lds, 0, wt, bias, mrow0, crow, kgrp, acc);
    write_h64(lds, 16384, acc, mrow0, crow, kgrp);
    __syncthreads();
    mm_pass64(lds, 16384, wt + 16384, bias + HD, mrow0, crow, kgrp, acc);
    #pragma unroll
    for (int n = 0; n < 8; ++n)
        #pragma unroll
        for (int rg = 0; rg < 4; ++rg)
            carry[n][rg] += silu_f(acc[n][rg]);
}

// ---- dual residual: out1 = bf16(x + mlpA(x)), out2 = bf16(x + mlpB(x)), coalesced bf16 stores ----
__global__ __launch_bounds__(256) void resid_dual_kernel(
    const float* __restrict__ x,
    const __bf16* __restrict__ wtA, const float* __restrict__ bA,
    const __bf16* __restrict__ wtB, const float* __restrict__ bB,
    __bf16* __restrict__ out1, __bf16* __restrict__ out2, int nrows)
{
    __shared__ char lds[32768];
    const int tid = threadIdx.x, lane = tid & 63, wv = tid >> 6;
    const int crow = lane & 15, kgrp = lane >> 4;
    const int r0 = blockIdx.x * 64, mrow0 = wv * 16;

    stage_x64(x, lds, r0, nrows, tid);
    __syncthreads();

    f32x4 acc[8], xe[8];
    // pass A
    mm_pass64(lds, 0, wtA, bA, mrow0, crow, kgrp, acc);
    write_h64(lds, 16384, acc, mrow0, crow, kgrp);
    __syncthreads();
    mm_pass64(lds, 16384, wtA + 16384, bA + HD, mrow0, crow, kgrp, acc);
    #pragma unroll
    for (int n = 0; n < 8; ++n)
        #pragma unroll
        for (int rg = 0; rg < 4; ++rg) {
            const int gr = r0 + mrow0 + kgrp*4 + rg;
            const int cc = n*16 + crow;
            float xv = (gr < nrows) ? x[(size_t)gr*HD + cc] : 0.f;
            xe[n][rg] = xv;
            *(__bf16*)(lds + 16384 + swz(mrow0 + kgrp*4 + rg, cc*2)) =
                (__bf16)(xv + silu_f(acc[n][rg]));
        }
    __syncthreads();
    {   // coalesced out1 store
        const int q = tid & 15;
        #pragma unroll
        for (int rr = 0; rr < 4; ++rr) {
            const int r = (tid >> 4) + rr * 16, gr = r0 + r;
            if (gr < nrows)
                *(bf16x8*)(out1 + (size_t)gr*HD + q*8) = *(const bf16x8*)(lds + 16384 + swz(r, q*16));
        }
    }
    // pass B (region0 still holds x)
    mm_pass64(lds, 0, wtB, bB, mrow0, crow, kgrp, acc);
    __syncthreads();                    // out1 bounce reads done before region1 overwrite
    write_h64(lds, 16384, acc, mrow0, crow, kgrp);
    __syncthreads();
    mm_pass64(lds, 16384, wtB + 16384, bB + HD, mrow0, crow, kgrp, acc);
    #pragma unroll
    for (int n = 0; n < 8; ++n)
        #pragma unroll
        for (int rg = 0; rg < 4; ++rg) {
            const int cc = n*16 + crow;
            *(__bf16*)(lds + swz(mrow0 + kgrp*4 + rg, cc*2)) =
                (__bf16)(xe[n][rg] + silu_f(acc[n][rg]));
        }
    __syncthreads();
    {   // coalesced out2 store (region0 bounce)
        const int q = tid & 15;
        #pragma unroll
        for (int rr = 0; rr < 4; ++rr) {
            const int r = (tid >> 4) + rr * 16, gr = r0 + r;
            if (gr < nrows)
                *(bf16x8*)(out2 + (size_t)gr*HD + q*8) = *(const bf16x8*)(lds + swz(r, q*16));
        }
    }
}

// ---- fused 4-block chain: y = post + R_D(R_C(mid ⊙ R_B(R_A(x)))) , f32 carry in registers ----
__global__ __launch_bounds__(256) void chain4_kernel(
    const float* __restrict__ x, const __bf16* __restrict__ mid,
    const __bf16* __restrict__ wA, const float* __restrict__ bA,
    const __bf16* __restrict__ wB, const float* __restrict__ bB,
    const __bf16* __restrict__ wC, const float* __restrict__ bC,
    const __bf16* __restrict__ wD, const float* __restrict__ bD,
    const float* __restrict__ post, float* __restrict__ y, int nrows)
{
    __shared__ char lds[32768];
    const int tid = threadIdx.x, lane = tid & 63, wv = tid >> 6;
    const int crow = lane & 15, kgrp = lane >> 4;
    const int r0 = blockIdx.x * 64, mrow0 = wv * 16;

    stage_x64(x, lds, r0, nrows, tid);
    __syncthreads();

    f32x4 carry[8];
    #pragma unroll
    for (int n = 0; n < 8; ++n)
        #pragma unroll
        for (int rg = 0; rg < 4; ++rg) {
            const int gr = r0 + mrow0 + kgrp*4 + rg;
            carry[n][rg] = (gr < nrows) ? x[(size_t)gr*HD + n*16 + crow] : 0.f;
        }

    sub_block(lds, wA, bA, mrow0, crow, kgrp, carry);
    restage64(lds, carry, mrow0, crow, kgrp);
    __syncthreads();
    sub_block(lds, wB, bB, mrow0, crow, kgrp, carry);
    #pragma unroll
    for (int n = 0; n < 8; ++n)
        #pragma unroll
        for (int rg = 0; rg < 4; ++rg) {
            const int gr = r0 + mrow0 + kgrp*4 + rg;
            const float m = (gr < nrows) ? (float)mid[(size_t)gr*HD + n*16 + crow] : 0.f;
            carry[n][rg] *= m;
        }
    restage64(lds, carry, mrow0, crow, kgrp);
    __syncthreads();
    sub_block(lds, wC, bC, mrow0, crow, kgrp, carry);
    restage64(lds, carry, mrow0, crow, kgrp);
    __syncthreads();
    sub_block(lds, wD, bD, mrow0, crow, kgrp, carry);
    #pragma unroll
    for (int n = 0; n < 8; ++n)
        #pragma unroll
        for (int rg = 0; rg < 4; ++rg) {
            const int gr = r0 + mrow0 + kgrp*4 + rg;
            if (gr < nrows) {
                const int cc = n*16 + crow;
                y[(size_t)gr*HD + cc] = carry[n][rg] + post[(size_t)gr*HD + cc];
            }
        }
}

// ---- single residual, f32 in/out (graph stage, tiny) ----
__global__ __launch_bounds__(256) void resid_single_kernel(
    const float* __restrict__ x, const __bf16* __restrict__ wt, const float* __restrict__ bias,
    float* __restrict__ y, int nrows)
{
    __shared__ char lds[32768];
    const int tid = threadIdx.x, lane = tid & 63, wv = tid >> 6;
    const int crow = lane & 15, kgrp = lane >> 4;
    const int r0 = blockIdx.x * 64, mrow0 = wv * 16;

    stage_x64(x, lds, r0, nrows, tid);
    __syncthreads();
    f32x4 acc[8];
    mm_pass64(lds, 0, wt, bias, mrow0, crow, kgrp, acc);
    write_h64(lds, 16384, acc, mrow0, crow, kgrp);
    __syncthreads();
    mm_pass64(lds, 16384, wt + 16384, bias + HD, mrow0, crow, kgrp, acc);
    #pragma unroll
    for (int n = 0; n < 8; ++n)
        #pragma unroll
        for (int rg = 0; rg < 4; ++rg) {
            const int gr = r0 + mrow0 + kgrp*4 + rg;
            if (gr < nrows) {
                const int cc = n*16 + crow;
                y[(size_t)gr*HD + cc] = x[(size_t)gr*HD + cc] + silu_f(acc[n][rg]);
            }
        }
}

// ---- CSR build ----
__global__ __launch_bounds__(256) void hist_kernel(const int* __restrict__ erow, int* __restrict__ cnt, int E) {
    int i = blockIdx.x * blockDim.x + threadIdx.x;
    const int stride = gridDim.x * blockDim.x;
    for (; i < E; i += stride) atomicAdd(&cnt[erow[i]], 1);
}

__global__ __launch_bounds__(256) void scan1_kernel(const int* __restrict__ cnt, int* __restrict__ part, int n) {
    __shared__ int red[256];
    const int base = blockIdx.x * 1024;
    int s = 0;
    for (int i = threadIdx.x; i < 1024; i += 256) {
        const int idx = base + i;
        s += (idx < n) ? cnt[idx] : 0;
    }
    red[threadIdx.x] = s; __syncthreads();
    for (int o = 128; o > 0; o >>= 1) {
        if (threadIdx.x < o) red[threadIdx.x] += red[threadIdx.x + o];
        __syncthreads();
    }
    if (threadIdx.x == 0) part[blockIdx.x] = red[0];
}

// parallel exclusive scan of up to 1024 chunk sums (1 block)
__global__ __launch_bounds__(256) void scan2_kernel(int* __restrict__ part, int nb,
                                                    int* __restrict__ rowptr, int n) {
    __shared__ int sh[257];
    const int tid = threadIdx.x;
    int a[4]; int s = 0;
    #pragma unroll
    for (int q = 0; q < 4; ++q) {
        const int i = tid*4 + q;
        a[q] = (i < nb) ? part[i] : 0;
        s += a[q];
    }
    sh[tid + 1] = s; __syncthreads();
    if (tid == 0) {
        sh[0] = 0;
        int run = 0;
        for (int i = 1; i <= 256; ++i) { run += sh[i]; sh[i] = run; }
    }
    __syncthreads();
    int off = sh[tid];
    #pragma unroll
    for (int q = 0; q < 4; ++q) {
        const int i = tid*4 + q;
        if (i < nb) part[i] = off;
        off += a[q];
    }
    if (tid == 255) rowptr[n] = off;
}

__global__ __launch_bounds__(256) void scan3_kernel(const int* __restrict__ cnt, const int* __restrict__ part,
                                                    int* __restrict__ rowptr, int n) {
    __shared__ int sc[257];
    const int base = blockIdx.x * 1024;
    const int i0 = base + threadIdx.x * 4;
    int v[4]; int s = 0;
    #pragma unroll
    for (int q = 0; q < 4; ++q) {
        const int idx = i0 + q;
        v[q] = (idx < n) ? cnt[idx] : 0;
        s += v[q];
    }
    sc[threadIdx.x + 1] = s; __syncthreads();
    if (threadIdx.x == 0) {
        int run = 0;
        for (int i = 0; i < 256; ++i) { const int t = sc[i + 1]; sc[i + 1] = run; run += t; }
    }
    __syncthreads();
    int off = part[blockIdx.x] + sc[threadIdx.x + 1];
    #pragma unroll
    for (int q = 0; q < 4; ++q) {
        const int idx = i0 + q;
        if (idx < n) rowptr[idx] = off;
        off += v[q];
    }
}

// scatter + reorder fused: csr_col[p] = ecol[i], csr_ef[p] = bf16(ef[i] * cs[i])
__global__ __launch_bounds__(256) void scatter_reorder_kernel(
    const int* __restrict__ erow, const int* __restrict__ ecol,
    const float* __restrict__ ef, const float* __restrict__ cs,
    const int* __restrict__ rowptr, int* __restrict__ cursor,
    int* __restrict__ csr_col, __bf16* __restrict__ csr_ef, int E)
{
    int i = blockIdx.x * blockDim.x + threadIdx.x;
    const int stride = gridDim.x * blockDim.x;
    for (; i < E; i += stride) {
        const int r = erow[i];
        const int p = rowptr[r] + atomicAdd(&cursor[r], 1);
        csr_col[p] = ecol[i];
        const float c = cs[i];
        const float4* ep = (const float4*)(ef + (size_t)i * 16);
        const float4 e0 = ep[0], e1 = ep[1], e2 = ep[2], e3 = ep[3];
        bf16x8 v0, v1;
        v0[0]=(__bf16)(e0.x*c); v0[1]=(__bf16)(e0.y*c); v0[2]=(__bf16)(e0.z*c); v0[3]=(__bf16)(e0.w*c);
        v0[4]=(__bf16)(e1.x*c); v0[5]=(__bf16)(e1.y*c); v0[6]=(__bf16)(e1.z*c); v0[7]=(__bf16)(e1.w*c);
        v1[0]=(__bf16)(e2.x*c); v1[1]=(__bf16)(e2.y*c); v1[2]=(__bf16)(e2.z*c); v1[3]=(__bf16)(e2.w*c);
        v1[4]=(__bf16)(e3.x*c); v1[5]=(__bf16)(e3.y*c); v1[6]=(__bf16)(e3.z*c); v1[7]=(__bf16)(e3.w*c);
        bf16x8* dst = (bf16x8*)(csr_ef + (size_t)p * 16);
        dst[0] = v0; dst[1] = v1;
    }
}

// ---- CSR gather conv: conv[v,j] = Cn[v] * Σ_t sdst16[col_t, j] * (csr_ef[t] @ w[:,j]) ----
__global__ __launch_bounds__(256) void conv_kernel(
    const __bf16* __restrict__ csr_ef, const int* __restrict__ csr_col,
    const float* __restrict__ elin, const int* __restrict__ rowptr,
    const __bf16* __restrict__ sdst, const float* __restrict__ Cn,
    float* __restrict__ conv, int nnodes)
{
    const int half = threadIdx.x >> 7;
    const int j = threadIdx.x & 127;
    const int v0 = blockIdx.x * 8 + half * 4;
    float w[16];
    #pragma unroll
    for (int k = 0; k < 16; ++k) w[k] = elin[k * HD + j];
    const int vend = (v0 + 4 < nnodes) ? v0 + 4 : nnodes;
    for (int v = v0; v < vend; ++v) {
        const int beg = rowptr[v], end = rowptr[v + 1];
        float acc = 0.f;
        if (beg < end) {
            int c = csr_col[beg];
            const bf16x8* ep = (const bf16x8*)(csr_ef + (size_t)beg * 16);
            bf16x8 e0 = ep[0], e1 = ep[1];
            for (int t = beg; t < end; ++t) {
                // prefetch next edge meta
                const int ts = (t + 1 < end) ? t + 1 : t;
                const int cn = csr_col[ts];
                const bf16x8* fp = (const bf16x8*)(csr_ef + (size_t)ts * 16);
                const bf16x8 f0 = fp[0], f1 = fp[1];
                float f = 0.f;
                #pragma unroll
                for (int k = 0; k < 8; ++k) f += (float)e0[k] * w[k];
                #pragma unroll
                for (int k = 0; k < 8; ++k) f += (float)e1[k] * w[8 + k];
                acc += (float)sdst[(size_t)c * HD + j] * f;
                c = cn; e0 = f0; e1 = f1;
            }
        }
        conv[(size_t)v * HD + j] = acc * Cn[v];
    }
}

// sorted segment-sum pooling
__global__ __launch_bounds__(128) void pool_kernel(
    const float* __restrict__ s, const int* __restrict__ bidx,
    float* __restrict__ g, int n)
{
    const int j = threadIdx.x;
    int i = blockIdx.x * 512;
    if (i >= n) return;
    const int end = (i + 512 < n) ? (i + 512) : n;
    float acc = 0.f;
    int cur = bidx[i];
    for (; i < end; ++i) {
        const int b = bidx[i];
        if (b != cur) { atomicAdd(g + (size_t)cur * HD + j, acc); acc = 0.f; cur = b; }
        acc += s[(size_t)i * HD + j];
    }
    atomicAdd(g + (size_t)cur * HD + j, acc);
}

// wt[mat][j][k] = (bf16) W[mat][k][j]
__global__ __launch_bounds__(256) void convw_kernel(const float* __restrict__ W, __bf16* __restrict__ wt, int total) {
    const int idx = blockIdx.x * 256 + threadIdx.x;
    if (idx >= total) return;
    const int mat = idx >> 14;
    const int rem = idx & 16383;
    const int jj = rem >> 7, kk = rem & 127;
    wt[idx] = (__bf16)W[(size_t)mat * 16384 + kk * HD + jj];
}

extern "C" void kernel_launch(void* const* d_in, const int* in_sizes, int n_in,
                              void* d_out, int out_size, void* d_ws, size_t ws_size,
                              hipStream_t stream) {
    const float* scalar = (const float*)d_in[0];
    const float* ef     = (const float*)d_in[1];
    const int*   eidx   = (const int*)  d_in[2];
    const float* Cn     = (const float*)d_in[3];
    const float* cs     = (const float*)d_in[4];
    const int*   bidx   = (const int*)  d_in[5];
    const float* resW   = (const float*)d_in[6];
    const float* resB   = (const float*)d_in[7];
    const float* elin   = (const float*)d_in[8];

    const int N      = in_sizes[0] / HD;
    const int E      = in_sizes[1] / 16;
    const int n_res  = in_sizes[7] / (2 * HD);
    const int layers = (n_res - 3) / 6;
    const int G      = out_size / HD;
    const size_t nfeat = (size_t)N * HD;

    char* p = (char*)d_ws;
    auto alloc = [&](size_t bytes) { char* q = p; p += (bytes + 255) & ~(size_t)255; return q; };
    float*  A      = (float*)alloc(nfeat * 4);
    float*  Dc     = (float*)alloc(nfeat * 4);
    __bf16* Bs16   = (__bf16*)alloc(nfeat * 2);      // s_src bf16
    __bf16* Cs16   = (__bf16*)alloc(nfeat * 2);      // s_dst bf16
    __bf16* wt     = (__bf16*)alloc((size_t)n_res * 2 * 16384 * 2);
    float*  graph  = (float*)alloc((size_t)G * HD * 4);
    int*    rowptr = (int*)alloc((size_t)(N + 1) * 4);
    int*    rowcnt = (int*)alloc((size_t)N * 4);
    int*    csr_col= (int*)alloc((size_t)E * 4);
    __bf16* csr_ef = (__bf16*)alloc((size_t)E * 16 * 2);
    int*    part   = (int*)alloc(1024 * 4);

    const int* erow = eidx;
    const int* ecol = eidx + E;

    const int totW = n_res * 2 * 16384;
    convw_kernel<<<(totW + 255) / 256, 256, 0, stream>>>(resW, wt, totW);

    // CSR build + edge-data reorder (once; shared by both layers)
    const int nchunks = (N + 1023) / 1024;
    hipMemsetAsync(rowcnt, 0, (size_t)N * 4, stream);
    hist_kernel<<<1024, 256, 0, stream>>>(erow, rowcnt, E);
    scan1_kernel<<<nchunks, 256, 0, stream>>>(rowcnt, part, N);
    scan2_kernel<<<1, 256, 0, stream>>>(part, nchunks, rowptr, N);
    scan3_kernel<<<nchunks, 256, 0, stream>>>(rowcnt, part, rowptr, N);
    hipMemsetAsync(rowcnt, 0, (size_t)N * 4, stream);
    scatter_reorder_kernel<<<1024, 256, 0, stream>>>(erow, ecol, ef, cs, rowptr, rowcnt, csr_col, csr_ef, E);

    const int gridR = (N + 63) / 64;
    const float* cur = scalar;
    for (int i = 0; i < layers; ++i) {
        const int pb = 6 * i;
        resid_dual_kernel<<<gridR, 256, 0, stream>>>(
            cur,
            wt + (size_t)pb * 32768, resB + (size_t)pb * 256,
            wt + (size_t)(pb + 1) * 32768, resB + (size_t)(pb + 1) * 256,
            Bs16, Cs16, N);
        conv_kernel<<<(N + 7) / 8, 256, 0, stream>>>(
            csr_ef, csr_col, elin + (size_t)i * 16 * HD, rowptr, Cs16, Cn, Dc, N);
        chain4_kernel<<<gridR, 256, 0, stream>>>(
            Dc, Bs16,
            wt + (size_t)(pb + 2) * 32768, resB + (size_t)(pb + 2) * 256,
            wt + (size_t)(pb + 3) * 32768, resB + (size_t)(pb + 3) * 256,
            wt + (size_t)(pb + 4) * 32768, resB + (size_t)(pb + 4) * 256,
            wt + (size_t)(pb + 5) * 32768, resB + (size_t)(pb + 5) * 256,
            cur, A, N);
        cur = A;
    }

    hipMemsetAsync(graph, 0, (size_t)G * HD * 4, stream);
    pool_kernel<<<(N + 511) / 512, 128, 0, stream>>>(cur, bidx, graph, N);

    const int q = 6 * layers;
    const int gridG = (G + 63) / 64;
    resid_single_kernel<<<gridG, 256, 0, stream>>>(graph, wt + (size_t)q * 32768, resB + (size_t)q * 256, graph, G);
    resid_single_kernel<<<gridG, 256, 0, stream>>>(graph, wt + (size_t)(q + 1) * 32768, resB + (size_t)(q + 1) * 256, graph, G);
    resid_single_kernel<<<gridG, 256, 0, stream>>>(graph, wt + (size_t)(q + 2) * 32768, resB + (size_t)(q + 2) * 256, (float*)d_out, G);
}

// Round 4
// 1819.083 us; speedup vs baseline: 1.7163x; 1.0176x over previous
//
#include <hip/hip_runtime.h>
#include <hip/hip_bf16.h>
#include <cstdint>
#include <cstddef>

#define HD 128

typedef __bf16    bf16x8 __attribute__((ext_vector_type(8)));
typedef float     f32x4  __attribute__((ext_vector_type(4)));
typedef _Float16  h2     __attribute__((ext_vector_type(2)));
typedef _Float16  h8     __attribute__((ext_vector_type(8)));

#if defined(__has_builtin)
#if __has_builtin(__builtin_amdgcn_fdot2)
#define HAVE_FDOT2 1
#endif
#endif

__device__ __forceinline__ float fdot2f(h2 a, h2 b, float c) {
#ifdef HAVE_FDOT2
    return __builtin_amdgcn_fdot2(a, b, c, false);
#else
    return c + (float)a[0]*(float)b[0] + (float)a[1]*(float)b[1];
#endif
}

// Swizzled LDS byte offset: row r (256B rows), byte-in-row b. chunk ^= (r&7) kills
// the stride-256B bank conflict on column-slice ds_read_b128.
__device__ __forceinline__ int swz(int r, int byteInRow) {
    int chunk = (byteInRow >> 4) ^ (r & 7);
    return r * 256 + (chunk << 4) + (byteInRow & 15);
}

__device__ __forceinline__ float silu_f(float v) { return v / (1.f + __expf(-v)); }

// ---- tile-64 residual building blocks (LDS: [0,16384) input bf16, [16384,32768) hidden bf16) ----

__device__ __forceinline__ void stage_x64(const float* __restrict__ x, char* lds,
                                          int r0, int nrows, int tid) {
    const int q = tid & 15;
    #pragma unroll
    for (int rr = 0; rr < 4; ++rr) {
        const int r  = (tid >> 4) + rr * 16;
        const int gr = r0 + r;
        float4 a = {0,0,0,0}, b = {0,0,0,0};
        if (gr < nrows) {
            const float4* p = (const float4*)(x + (size_t)gr * HD + q * 8);
            a = p[0]; b = p[1];
        }
        bf16x8 v;
        v[0]=(__bf16)a.x; v[1]=(__bf16)a.y; v[2]=(__bf16)a.z; v[3]=(__bf16)a.w;
        v[4]=(__bf16)b.x; v[5]=(__bf16)b.y; v[6]=(__bf16)b.z; v[7]=(__bf16)b.w;
        *(bf16x8*)(lds + swz(r, q * 16)) = v;
    }
}

__device__ __forceinline__ void mm_pass64(const char* lds, int off,
                                          const __bf16* __restrict__ wt, const float* __restrict__ bias,
                                          int mrow0, int crow, int kgrp, f32x4 acc[8]) {
    bf16x8 afr[4];
    #pragma unroll
    for (int kk = 0; kk < 4; ++kk)
        afr[kk] = *(const bf16x8*)(lds + off + swz(mrow0 + crow, kk*64 + kgrp*16));
    #pragma unroll
    for (int n = 0; n < 8; ++n) {
        const float bv = bias[n * 16 + crow];
        f32x4 t = {bv, bv, bv, bv};
        acc[n] = t;
    }
    #pragma unroll
    for (int n = 0; n < 8; ++n) {
        bf16x8 bfr[4];
        #pragma unroll
        for (int kk = 0; kk < 4; ++kk)
            bfr[kk] = *(const bf16x8*)(wt + (size_t)(n*16 + crow)*HD + kk*32 + kgrp*8);
        #pragma unroll
        for (int kk = 0; kk < 4; ++kk)
            acc[n] = __builtin_amdgcn_mfma_f32_16x16x32_bf16(afr[kk], bfr[kk], acc[n], 0, 0, 0);
    }
}

__device__ __forceinline__ void write_h64(char* lds, int off, const f32x4 acc[8],
                                          int mrow0, int crow, int kgrp) {
    #pragma unroll
    for (int n = 0; n < 8; ++n)
        #pragma unroll
        for (int rg = 0; rg < 4; ++rg)
            *(__bf16*)(lds + off + swz(mrow0 + kgrp*4 + rg, (n*16 + crow)*2)) =
                (__bf16)silu_f(acc[n][rg]);
}

__device__ __forceinline__ void restage64(char* lds, const f32x4 carry[8],
                                          int mrow0, int crow, int kgrp) {
    #pragma unroll
    for (int n = 0; n < 8; ++n)
        #pragma unroll
        for (int rg = 0; rg < 4; ++rg)
            *(__bf16*)(lds + swz(mrow0 + kgrp*4 + rg, (n*16 + crow)*2)) =
                (__bf16)carry[n][rg];
}

// carry += silu(mlp(region0))
__device__ __forceinline__ void sub_block(char* lds, const __bf16* __restrict__ wt,
                                          const float* __restrict__ bias,
                                          int mrow0, int crow, int kgrp, f32x4 carry[8]) {
    f32x4 acc[8];
    mm_pass64(lds, 0, wt, bias, mrow0, crow, kgrp, acc);
    write_h64(lds, 16384, acc, mrow0, crow, kgrp);
    __syncthreads();
    mm_pass64(lds, 16384, wt + 16384, bias + HD, mrow0, crow, kgrp, acc);
    #pragma unroll
    for (int n = 0; n < 8; ++n)
        #pragma unroll
        for (int rg = 0; rg < 4; ++rg)
            carry[n][rg] += silu_f(acc[n][rg]);
}

// ---- dual residual: out1 = bf16(x + mlpA(x)), out2 = bf16(x + mlpB(x)), coalesced bf16 stores ----
__global__ __launch_bounds__(256) void resid_dual_kernel(
    const float* __restrict__ x,
    const __bf16* __restrict__ wtA, const float* __restrict__ bA,
    const __bf16* __restrict__ wtB, const float* __restrict__ bB,
    __bf16* __restrict__ out1, __bf16* __restrict__ out2, int nrows)
{
    __shared__ char lds[32768];
    const int tid = threadIdx.x, lane = tid & 63, wv = tid >> 6;
    const int crow = lane & 15, kgrp = lane >> 4;
    const int r0 = blockIdx.x * 64, mrow0 = wv * 16;

    stage_x64(x, lds, r0, nrows, tid);
    __syncthreads();

    f32x4 acc[8], xe[8];
    // pass A
    mm_pass64(lds, 0, wtA, bA, mrow0, crow, kgrp, acc);
    write_h64(lds, 16384, acc, mrow0, crow, kgrp);
    __syncthreads();
    mm_pass64(lds, 16384, wtA + 16384, bA + HD, mrow0, crow, kgrp, acc);
    #pragma unroll
    for (int n = 0; n < 8; ++n)
        #pragma unroll
        for (int rg = 0; rg < 4; ++rg) {
            const int gr = r0 + mrow0 + kgrp*4 + rg;
            const int cc = n*16 + crow;
            float xv = (gr < nrows) ? x[(size_t)gr*HD + cc] : 0.f;
            xe[n][rg] = xv;
            *(__bf16*)(lds + 16384 + swz(mrow0 + kgrp*4 + rg, cc*2)) =
                (__bf16)(xv + silu_f(acc[n][rg]));
        }
    __syncthreads();
    {   // coalesced out1 store
        const int q = tid & 15;
        #pragma unroll
        for (int rr = 0; rr < 4; ++rr) {
            const int r = (tid >> 4) + rr * 16, gr = r0 + r;
            if (gr < nrows)
                *(bf16x8*)(out1 + (size_t)gr*HD + q*8) = *(const bf16x8*)(lds + 16384 + swz(r, q*16));
        }
    }
    // pass B (region0 still holds x)
    mm_pass64(lds, 0, wtB, bB, mrow0, crow, kgrp, acc);
    __syncthreads();                    // out1 bounce reads done before region1 overwrite
    write_h64(lds, 16384, acc, mrow0, crow, kgrp);
    __syncthreads();
    mm_pass64(lds, 16384, wtB + 16384, bB + HD, mrow0, crow, kgrp, acc);
    #pragma unroll
    for (int n = 0; n < 8; ++n)
        #pragma unroll
        for (int rg = 0; rg < 4; ++rg) {
            const int cc = n*16 + crow;
            *(__bf16*)(lds + swz(mrow0 + kgrp*4 + rg, cc*2)) =
                (__bf16)(xe[n][rg] + silu_f(acc[n][rg]));
        }
    __syncthreads();
    {   // coalesced out2 store (region0 bounce)
        const int q = tid & 15;
        #pragma unroll
        for (int rr = 0; rr < 4; ++rr) {
            const int r = (tid >> 4) + rr * 16, gr = r0 + r;
            if (gr < nrows)
                *(bf16x8*)(out2 + (size_t)gr*HD + q*8) = *(const bf16x8*)(lds + swz(r, q*16));
        }
    }
}

// ---- fused 4-block chain: y = post + R_D(R_C(mid ⊙ R_B(R_A(x)))) , f32 carry in registers ----
__global__ __launch_bounds__(256) void chain4_kernel(
    const float* __restrict__ x, const __bf16* __restrict__ mid,
    const __bf16* __restrict__ wA, const float* __restrict__ bA,
    const __bf16* __restrict__ wB, const float* __restrict__ bB,
    const __bf16* __restrict__ wC, const float* __restrict__ bC,
    const __bf16* __restrict__ wD, const float* __restrict__ bD,
    const float* __restrict__ post, float* __restrict__ y, int nrows)
{
    __shared__ char lds[32768];
    const int tid = threadIdx.x, lane = tid & 63, wv = tid >> 6;
    const int crow = lane & 15, kgrp = lane >> 4;
    const int r0 = blockIdx.x * 64, mrow0 = wv * 16;

    stage_x64(x, lds, r0, nrows, tid);
    __syncthreads();

    f32x4 carry[8];
    #pragma unroll
    for (int n = 0; n < 8; ++n)
        #pragma unroll
        for (int rg = 0; rg < 4; ++rg) {
            const int gr = r0 + mrow0 + kgrp*4 + rg;
            carry[n][rg] = (gr < nrows) ? x[(size_t)gr*HD + n*16 + crow] : 0.f;
        }

    sub_block(lds, wA, bA, mrow0, crow, kgrp, carry);
    restage64(lds, carry, mrow0, crow, kgrp);
    __syncthreads();
    sub_block(lds, wB, bB, mrow0, crow, kgrp, carry);
    #pragma unroll
    for (int n = 0; n < 8; ++n)
        #pragma unroll
        for (int rg = 0; rg < 4; ++rg) {
            const int gr = r0 + mrow0 + kgrp*4 + rg;
            const float m = (gr < nrows) ? (float)mid[(size_t)gr*HD + n*16 + crow] : 0.f;
            carry[n][rg] *= m;
        }
    restage64(lds, carry, mrow0, crow, kgrp);
    __syncthreads();
    sub_block(lds, wC, bC, mrow0, crow, kgrp, carry);
    restage64(lds, carry, mrow0, crow, kgrp);
    __syncthreads();
    sub_block(lds, wD, bD, mrow0, crow, kgrp, carry);
    #pragma unroll
    for (int n = 0; n < 8; ++n)
        #pragma unroll
        for (int rg = 0; rg < 4; ++rg) {
            const int gr = r0 + mrow0 + kgrp*4 + rg;
            if (gr < nrows) {
                const int cc = n*16 + crow;
                y[(size_t)gr*HD + cc] = carry[n][rg] + post[(size_t)gr*HD + cc];
            }
        }
}

// ---- fused 3-block graph chain: out = R_C(R_B(R_A(x))) ----
__global__ __launch_bounds__(256) void chain3_kernel(
    const float* __restrict__ x,
    const __bf16* __restrict__ wA, const float* __restrict__ bA,
    const __bf16* __restrict__ wB, const float* __restrict__ bB,
    const __bf16* __restrict__ wC, const float* __restrict__ bC,
    float* __restrict__ y, int nrows)
{
    __shared__ char lds[32768];
    const int tid = threadIdx.x, lane = tid & 63, wv = tid >> 6;
    const int crow = lane & 15, kgrp = lane >> 4;
    const int r0 = blockIdx.x * 64, mrow0 = wv * 16;

    stage_x64(x, lds, r0, nrows, tid);
    __syncthreads();

    f32x4 carry[8];
    #pragma unroll
    for (int n = 0; n < 8; ++n)
        #pragma unroll
        for (int rg = 0; rg < 4; ++rg) {
            const int gr = r0 + mrow0 + kgrp*4 + rg;
            carry[n][rg] = (gr < nrows) ? x[(size_t)gr*HD + n*16 + crow] : 0.f;
        }
    sub_block(lds, wA, bA, mrow0, crow, kgrp, carry);
    restage64(lds, carry, mrow0, crow, kgrp);
    __syncthreads();
    sub_block(lds, wB, bB, mrow0, crow, kgrp, carry);
    restage64(lds, carry, mrow0, crow, kgrp);
    __syncthreads();
    sub_block(lds, wC, bC, mrow0, crow, kgrp, carry);
    #pragma unroll
    for (int n = 0; n < 8; ++n)
        #pragma unroll
        for (int rg = 0; rg < 4; ++rg) {
            const int gr = r0 + mrow0 + kgrp*4 + rg;
            if (gr < nrows)
                y[(size_t)gr*HD + n*16 + crow] = carry[n][rg];
        }
}

// ---- CSR build ----
__global__ __launch_bounds__(256) void hist_kernel(const int* __restrict__ erow, int* __restrict__ cnt, int E) {
    int i = blockIdx.x * blockDim.x + threadIdx.x;
    const int stride = gridDim.x * blockDim.x;
    for (; i < E; i += stride) atomicAdd(&cnt[erow[i]], 1);
}

__global__ __launch_bounds__(256) void scan1_kernel(const int* __restrict__ cnt, int* __restrict__ part, int n) {
    __shared__ int red[256];
    const int base = blockIdx.x * 1024;
    int s = 0;
    for (int i = threadIdx.x; i < 1024; i += 256) {
        const int idx = base + i;
        s += (idx < n) ? cnt[idx] : 0;
    }
    red[threadIdx.x] = s; __syncthreads();
    for (int o = 128; o > 0; o >>= 1) {
        if (threadIdx.x < o) red[threadIdx.x] += red[threadIdx.x + o];
        __syncthreads();
    }
    if (threadIdx.x == 0) part[blockIdx.x] = red[0];
}

__global__ __launch_bounds__(256) void scan2_kernel(int* __restrict__ part, int nb,
                                                    int* __restrict__ rowptr, int n) {
    __shared__ int sh[257];
    const int tid = threadIdx.x;
    int a[4]; int s = 0;
    #pragma unroll
    for (int q = 0; q < 4; ++q) {
        const int i = tid*4 + q;
        a[q] = (i < nb) ? part[i] : 0;
        s += a[q];
    }
    sh[tid + 1] = s; __syncthreads();
    if (tid == 0) {
        sh[0] = 0;
        int run = 0;
        for (int i = 1; i <= 256; ++i) { run += sh[i]; sh[i] = run; }
    }
    __syncthreads();
    int off = sh[tid];
    #pragma unroll
    for (int q = 0; q < 4; ++q) {
        const int i = tid*4 + q;
        if (i < nb) part[i] = off;
        off += a[q];
    }
    if (tid == 255) rowptr[n] = off;
}

__global__ __launch_bounds__(256) void scan3_kernel(const int* __restrict__ cnt, const int* __restrict__ part,
                                                    int* __restrict__ rowptr, int n) {
    __shared__ int sc[257];
    const int base = blockIdx.x * 1024;
    const int i0 = base + threadIdx.x * 4;
    int v[4]; int s = 0;
    #pragma unroll
    for (int q = 0; q < 4; ++q) {
        const int idx = i0 + q;
        v[q] = (idx < n) ? cnt[idx] : 0;
        s += v[q];
    }
    sc[threadIdx.x + 1] = s; __syncthreads();
    if (threadIdx.x == 0) {
        int run = 0;
        for (int i = 0; i < 256; ++i) { const int t = sc[i + 1]; sc[i + 1] = run; run += t; }
    }
    __syncthreads();
    int off = part[blockIdx.x] + sc[threadIdx.x + 1];
    #pragma unroll
    for (int q = 0; q < 4; ++q) {
        const int idx = i0 + q;
        if (idx < n) rowptr[idx] = off;
        off += v[q];
    }
}

// scatter + reorder fused: csr_col[p] = ecol[i], csr_ef[p] = fp16(ef[i] * cs[i])
__global__ __launch_bounds__(256) void scatter_reorder_kernel(
    const int* __restrict__ erow, const int* __restrict__ ecol,
    const float* __restrict__ ef, const float* __restrict__ cs,
    const int* __restrict__ rowptr, int* __restrict__ cursor,
    int* __restrict__ csr_col, _Float16* __restrict__ csr_ef, int E)
{
    int i = blockIdx.x * blockDim.x + threadIdx.x;
    const int stride = gridDim.x * blockDim.x;
    for (; i < E; i += stride) {
        const int r = erow[i];
        const int p = rowptr[r] + atomicAdd(&cursor[r], 1);
        csr_col[p] = ecol[i];
        const float c = cs[i];
        const float4* ep = (const float4*)(ef + (size_t)i * 16);
        const float4 e0 = ep[0], e1 = ep[1], e2 = ep[2], e3 = ep[3];
        h8 v0, v1;
        v0[0]=(_Float16)(e0.x*c); v0[1]=(_Float16)(e0.y*c); v0[2]=(_Float16)(e0.z*c); v0[3]=(_Float16)(e0.w*c);
        v0[4]=(_Float16)(e1.x*c); v0[5]=(_Float16)(e1.y*c); v0[6]=(_Float16)(e1.z*c); v0[7]=(_Float16)(e1.w*c);
        v1[0]=(_Float16)(e2.x*c); v1[1]=(_Float16)(e2.y*c); v1[2]=(_Float16)(e2.z*c); v1[3]=(_Float16)(e2.w*c);
        v1[4]=(_Float16)(e3.x*c); v1[5]=(_Float16)(e3.y*c); v1[6]=(_Float16)(e3.z*c); v1[7]=(_Float16)(e3.w*c);
        h8* dst = (h8*)(csr_ef + (size_t)p * 16);
        dst[0] = v0; dst[1] = v1;
    }
}

// elin f32 [16][128] -> fp16 (per layer)
__global__ __launch_bounds__(256) void elin16_kernel(const float* __restrict__ elin,
                                                     _Float16* __restrict__ out, int total) {
    const int i = blockIdx.x * 256 + threadIdx.x;
    if (i < total) out[i] = (_Float16)elin[i];
}

// ---- CSR gather conv: conv[v,j] = Cn[v] * Σ_t sdst[col_t, j] * (csr_ef[t] @ w[:,j]) ----
__global__ __launch_bounds__(256) void conv_kernel(
    const _Float16* __restrict__ csr_ef, const int* __restrict__ csr_col,
    const _Float16* __restrict__ elin16, const int* __restrict__ rowptr,
    const __bf16* __restrict__ sdst, const float* __restrict__ Cn,
    float* __restrict__ conv, int nnodes)
{
    const int half = threadIdx.x >> 7;
    const int j = threadIdx.x & 127;
    const int v0 = blockIdx.x * 8 + half * 4;
    h2 w2[8];
    #pragma unroll
    for (int k = 0; k < 8; ++k) {
        w2[k][0] = elin16[(2*k)   * HD + j];
        w2[k][1] = elin16[(2*k+1) * HD + j];
    }
    const int vend = (v0 + 4 < nnodes) ? v0 + 4 : nnodes;
    for (int v = v0; v < vend; ++v) {
        const int beg = rowptr[v], end = rowptr[v + 1];
        float acc = 0.f;
        int t = beg;
        for (; t + 2 <= end; t += 2) {
            const int c0 = csr_col[t], c1 = csr_col[t + 1];
            const h8* ep = (const h8*)(csr_ef + (size_t)t * 16);
            const h8 a0 = ep[0], a1 = ep[1], b0 = ep[2], b1 = ep[3];
            const float s0 = (float)sdst[(size_t)c0 * HD + j];
            const float s1 = (float)sdst[(size_t)c1 * HD + j];
            float f0 = 0.f, f1 = 0.f;
            #pragma unroll
            for (int k = 0; k < 4; ++k) {
                h2 p = {a0[2*k], a0[2*k+1]};
                f0 = fdot2f(p, w2[k], f0);
            }
            #pragma unroll
            for (int k = 0; k < 4; ++k) {
                h2 p = {a1[2*k], a1[2*k+1]};
                f0 = fdot2f(p, w2[4 + k], f0);
            }
            #pragma unroll
            for (int k = 0; k < 4; ++k) {
                h2 p = {b0[2*k], b0[2*k+1]};
                f1 = fdot2f(p, w2[k], f1);
            }
            #pragma unroll
            for (int k = 0; k < 4; ++k) {
                h2 p = {b1[2*k], b1[2*k+1]};
                f1 = fdot2f(p, w2[4 + k], f1);
            }
            acc = fmaf(s0, f0, acc);
            acc = fmaf(s1, f1, acc);
        }
        if (t < end) {
            const int c0 = csr_col[t];
            const h8* ep = (const h8*)(csr_ef + (size_t)t * 16);
            const h8 a0 = ep[0], a1 = ep[1];
            const float s0 = (float)sdst[(size_t)c0 * HD + j];
            float f0 = 0.f;
            #pragma unroll
            for (int k = 0; k < 4; ++k) {
                h2 p = {a0[2*k], a0[2*k+1]};
                f0 = fdot2f(p, w2[k], f0);
            }
            #pragma unroll
            for (int k = 0; k < 4; ++k) {
                h2 p = {a1[2*k], a1[2*k+1]};
                f0 = fdot2f(p, w2[4 + k], f0);
            }
            acc = fmaf(s0, f0, acc);
        }
        conv[(size_t)v * HD + j] = acc * Cn[v];
    }
}

// sorted segment-sum pooling: 256 thr = 8 row-slots x 32 col-quads; per-thread running acc
__global__ __launch_bounds__(256) void pool_kernel(
    const float* __restrict__ s, const int* __restrict__ bidx,
    float* __restrict__ g, int n)
{
    const int slot = threadIdx.x >> 5;           // 0..7
    const int jc   = (threadIdx.x & 31) * 4;     // col quad
    const int base = blockIdx.x * 256;
    if (base >= n) return;
    const int end = (base + 256 < n) ? base + 256 : n;
    float4 acc = {0,0,0,0};
    int cur = -1;
    for (int i = base + slot; i < end; i += 8) {
        const int b = bidx[i];
        if (b != cur) {
            if (cur >= 0) {
                atomicAdd(g + (size_t)cur*HD + jc + 0, acc.x);
                atomicAdd(g + (size_t)cur*HD + jc + 1, acc.y);
                atomicAdd(g + (size_t)cur*HD + jc + 2, acc.z);
                atomicAdd(g + (size_t)cur*HD + jc + 3, acc.w);
            }
            acc = {0,0,0,0};
            cur = b;
        }
        const float4 v = *(const float4*)(s + (size_t)i*HD + jc);
        acc.x += v.x; acc.y += v.y; acc.z += v.z; acc.w += v.w;
    }
    if (cur >= 0) {
        atomicAdd(g + (size_t)cur*HD + jc + 0, acc.x);
        atomicAdd(g + (size_t)cur*HD + jc + 1, acc.y);
        atomicAdd(g + (size_t)cur*HD + jc + 2, acc.z);
        atomicAdd(g + (size_t)cur*HD + jc + 3, acc.w);
    }
}

// wt[mat][j][k] = (bf16) W[mat][k][j]
__global__ __launch_bounds__(256) void convw_kernel(const float* __restrict__ W, __bf16* __restrict__ wt, int total) {
    const int idx = blockIdx.x * 256 + threadIdx.x;
    if (idx >= total) return;
    const int mat = idx >> 14;
    const int rem = idx & 16383;
    const int jj = rem >> 7, kk = rem & 127;
    wt[idx] = (__bf16)W[(size_t)mat * 16384 + kk * HD + jj];
}

extern "C" void kernel_launch(void* const* d_in, const int* in_sizes, int n_in,
                              void* d_out, int out_size, void* d_ws, size_t ws_size,
                              hipStream_t stream) {
    const float* scalar = (const float*)d_in[0];
    const float* ef     = (const float*)d_in[1];
    const int*   eidx   = (const int*)  d_in[2];
    const float* Cn     = (const float*)d_in[3];
    const float* cs     = (const float*)d_in[4];
    const int*   bidx   = (const int*)  d_in[5];
    const float* resW   = (const float*)d_in[6];
    const float* resB   = (const float*)d_in[7];
    const float* elin   = (const float*)d_in[8];

    const int N      = in_sizes[0] / HD;
    const int E      = in_sizes[1] / 16;
    const int n_res  = in_sizes[7] / (2 * HD);
    const int layers = (n_res - 3) / 6;
    const int G      = out_size / HD;
    const size_t nfeat = (size_t)N * HD;

    char* p = (char*)d_ws;
    auto alloc = [&](size_t bytes) { char* q = p; p += (bytes + 255) & ~(size_t)255; return q; };
    float*    A      = (float*)alloc(nfeat * 4);
    float*    Dc     = (float*)alloc(nfeat * 4);
    __bf16*   Bs16   = (__bf16*)alloc(nfeat * 2);      // s_src bf16
    __bf16*   Cs16   = (__bf16*)alloc(nfeat * 2);      // s_dst bf16
    __bf16*   wt     = (__bf16*)alloc((size_t)n_res * 2 * 16384 * 2);
    float*    graph  = (float*)alloc((size_t)G * HD * 4);
    int*      rowptr = (int*)alloc((size_t)(N + 1) * 4);
    int*      rowcnt = (int*)alloc((size_t)N * 4);
    int*      csr_col= (int*)alloc((size_t)E * 4);
    _Float16* csr_ef = (_Float16*)alloc((size_t)E * 16 * 2);
    _Float16* elin16 = (_Float16*)alloc((size_t)layers * 16 * HD * 2);
    int*      part   = (int*)alloc(1024 * 4);

    const int* erow = eidx;
    const int* ecol = eidx + E;

    const int totW = n_res * 2 * 16384;
    convw_kernel<<<(totW + 255) / 256, 256, 0, stream>>>(resW, wt, totW);
    const int totE = layers * 16 * HD;
    elin16_kernel<<<(totE + 255) / 256, 256, 0, stream>>>(elin, elin16, totE);

    // CSR build + edge-data reorder (once; shared by both layers)
    const int nchunks = (N + 1023) / 1024;
    hipMemsetAsync(rowcnt, 0, (size_t)N * 4, stream);
    hist_kernel<<<1024, 256, 0, stream>>>(erow, rowcnt, E);
    scan1_kernel<<<nchunks, 256, 0, stream>>>(rowcnt, part, N);
    scan2_kernel<<<1, 256, 0, stream>>>(part, nchunks, rowptr, N);
    scan3_kernel<<<nchunks, 256, 0, stream>>>(rowcnt, part, rowptr, N);
    hipMemsetAsync(rowcnt, 0, (size_t)N * 4, stream);
    scatter_reorder_kernel<<<1024, 256, 0, stream>>>(erow, ecol, ef, cs, rowptr, rowcnt, csr_col, csr_ef, E);

    const int gridR = (N + 63) / 64;
    const float* cur = scalar;
    for (int i = 0; i < layers; ++i) {
        const int pb = 6 * i;
        resid_dual_kernel<<<gridR, 256, 0, stream>>>(
            cur,
            wt + (size_t)pb * 32768, resB + (size_t)pb * 256,
            wt + (size_t)(pb + 1) * 32768, resB + (size_t)(pb + 1) * 256,
            Bs16, Cs16, N);
        conv_kernel<<<(N + 7) / 8, 256, 0, stream>>>(
            csr_ef, csr_col, elin16 + (size_t)i * 16 * HD, rowptr, Cs16, Cn, Dc, N);
        chain4_kernel<<<gridR, 256, 0, stream>>>(
            Dc, Bs16,
            wt + (size_t)(pb + 2) * 32768, resB + (size_t)(pb + 2) * 256,
            wt + (size_t)(pb + 3) * 32768, resB + (size_t)(pb + 3) * 256,
            wt + (size_t)(pb + 4) * 32768, resB + (size_t)(pb + 4) * 256,
            wt + (size_t)(pb + 5) * 32768, resB + (size_t)(pb + 5) * 256,
            cur, A, N);
        cur = A;
    }

    hipMemsetAsync(graph, 0, (size_t)G * HD * 4, stream);
    pool_kernel<<<(N + 255) / 256, 256, 0, stream>>>(cur, bidx, graph, N);

    const int q = 6 * layers;
    const int gridG = (G + 63) / 64;
    chain3_kernel<<<gridG, 256, 0, stream>>>(
        graph,
        wt + (size_t)q * 32768, resB + (size_t)q * 256,
        wt + (size_t)(q + 1) * 32768, resB + (size_t)(q + 1) * 256,
        wt + (size_t)(q + 2) * 32768, resB + (size_t)(q + 2) * 256,
        (float*)d_out, G);
}

// Round 5
// 1410.657 us; speedup vs baseline: 2.2132x; 1.2895x over previous
//
#include <hip/hip_runtime.h>
#include <hip/hip_bf16.h>
#include <cstdint>
#include <cstddef>

#define HD 128
#define WOFF 32768   // W tile region in LDS

typedef __bf16    bf16x8 __attribute__((ext_vector_type(8)));
typedef float     f32x4  __attribute__((ext_vector_type(4)));
typedef _Float16  h2     __attribute__((ext_vector_type(2)));
typedef _Float16  h8     __attribute__((ext_vector_type(8)));

#if defined(__has_builtin)
#if __has_builtin(__builtin_amdgcn_fdot2)
#define HAVE_FDOT2 1
#endif
#endif

__device__ __forceinline__ float fdot2f(h2 a, h2 b, float c) {
#ifdef HAVE_FDOT2
    return __builtin_amdgcn_fdot2(a, b, c, false);
#else
    return c + (float)a[0]*(float)b[0] + (float)a[1]*(float)b[1];
#endif
}

// Swizzled LDS byte offset: row r (256B rows), byte-in-row b. chunk ^= (r&7) kills
// the stride-256B bank conflict on column-slice ds_read_b128.
__device__ __forceinline__ int swz(int r, int byteInRow) {
    int chunk = (byteInRow >> 4) ^ (r & 7);
    return r * 256 + (chunk << 4) + (byteInRow & 15);
}

__device__ __forceinline__ float silu_f(float v) { return v / (1.f + __expf(-v)); }

// ---- W tile staging: 32KB matrix, 256 threads x 8 chunks of 16B, reg round-trip ----
__device__ __forceinline__ void load_wpref(const __bf16* __restrict__ w, bf16x8 pref[8], int tid) {
    #pragma unroll
    for (int i = 0; i < 8; ++i)
        pref[i] = *(const bf16x8*)(w + (size_t)(i * 256 + tid) * 8);
}
__device__ __forceinline__ void store_wpref(char* lds, const bf16x8 pref[8], int tid) {
    #pragma unroll
    for (int i = 0; i < 8; ++i) {
        const int l = i * 256 + tid;
        *(bf16x8*)(lds + WOFF + swz(l >> 4, (l & 15) * 16)) = pref[i];
    }
}

// ---- 64-row tile blocks. LDS: [0,16K) region0 (x/carry), [16K,32K) region1 (h), [32K,64K) Wbuf ----

__device__ __forceinline__ void stage_x64(const float* __restrict__ x, char* lds,
                                          int r0, int nrows, int tid) {
    const int q = tid & 15;
    #pragma unroll
    for (int rr = 0; rr < 4; ++rr) {
        const int r  = (tid >> 4) + rr * 16;
        const int gr = r0 + r;
        float4 a = {0,0,0,0}, b = {0,0,0,0};
        if (gr < nrows) {
            const float4* p = (const float4*)(x + (size_t)gr * HD + q * 8);
            a = p[0]; b = p[1];
        }
        bf16x8 v;
        v[0]=(__bf16)a.x; v[1]=(__bf16)a.y; v[2]=(__bf16)a.z; v[3]=(__bf16)a.w;
        v[4]=(__bf16)b.x; v[5]=(__bf16)b.y; v[6]=(__bf16)b.z; v[7]=(__bf16)b.w;
        *(bf16x8*)(lds + swz(r, q * 16)) = v;
    }
}

// acc = (region[src_off] @ Wbuf) + bias; A-frags own-wave rows, B-frags from staged W
__device__ __forceinline__ void mm_pass_lds(const char* lds, int src_off,
                                            const float* __restrict__ bias,
                                            int mrow0, int crow, int kgrp, f32x4 acc[8]) {
    bf16x8 afr[4];
    #pragma unroll
    for (int kk = 0; kk < 4; ++kk)
        afr[kk] = *(const bf16x8*)(lds + src_off + swz(mrow0 + crow, kk*64 + kgrp*16));
    #pragma unroll
    for (int n = 0; n < 8; ++n) {
        const float bv = bias[n * 16 + crow];
        f32x4 t = {bv, bv, bv, bv};
        acc[n] = t;
    }
    #pragma unroll
    for (int n = 0; n < 8; ++n) {
        #pragma unroll
        for (int kk = 0; kk < 4; ++kk) {
            const bf16x8 bfr = *(const bf16x8*)(lds + WOFF + swz(n*16 + crow, kk*64 + kgrp*16));
            acc[n] = __builtin_amdgcn_mfma_f32_16x16x32_bf16(afr[kk], bfr, acc[n], 0, 0, 0);
        }
    }
}

__device__ __forceinline__ void write_h64(char* lds, int off, const f32x4 acc[8],
                                          int mrow0, int crow, int kgrp) {
    #pragma unroll
    for (int n = 0; n < 8; ++n)
        #pragma unroll
        for (int rg = 0; rg < 4; ++rg)
            *(__bf16*)(lds + off + swz(mrow0 + kgrp*4 + rg, (n*16 + crow)*2)) =
                (__bf16)silu_f(acc[n][rg]);
}

__device__ __forceinline__ void restage64(char* lds, const f32x4 carry[8],
                                          int mrow0, int crow, int kgrp) {
    #pragma unroll
    for (int n = 0; n < 8; ++n)
        #pragma unroll
        for (int rg = 0; rg < 4; ++rg)
            *(__bf16*)(lds + swz(mrow0 + kgrp*4 + rg, (n*16 + crow)*2)) =
                (__bf16)carry[n][rg];
}

// pass1 of a residual sub-block: h = silu(region0 @ Wbuf + b); prefetch w1next into Wbuf
__device__ __forceinline__ void sb_pass1(char* lds, const __bf16* __restrict__ w1next,
                                         const float* __restrict__ bias,
                                         int tid, int mrow0, int crow, int kgrp, f32x4 acc[8]) {
    bf16x8 pref[8];
    load_wpref(w1next, pref, tid);
    mm_pass_lds(lds, 0, bias, mrow0, crow, kgrp, acc);
    write_h64(lds, 16384, acc, mrow0, crow, kgrp);
    __syncthreads();
    store_wpref(lds, pref, tid);
    __syncthreads();
}

__device__ __forceinline__ void bounce_store(const char* lds, int off, __bf16* __restrict__ out,
                                             int r0, int nrows, int tid) {
    const int q = tid & 15;
    #pragma unroll
    for (int rr = 0; rr < 4; ++rr) {
        const int r = (tid >> 4) + rr * 16, gr = r0 + r;
        if (gr < nrows)
            *(bf16x8*)(out + (size_t)gr * HD + q * 8) = *(const bf16x8*)(lds + off + swz(r, q * 16));
    }
}

// ---- dual residual: out1 = bf16(x + mlpA(x)), out2 = bf16(x + mlpB(x)) ----
__global__ __launch_bounds__(256) void resid_dual_kernel(
    const float* __restrict__ x,
    const __bf16* __restrict__ wtA, const float* __restrict__ bA,
    const __bf16* __restrict__ wtB, const float* __restrict__ bB,
    __bf16* __restrict__ out1, __bf16* __restrict__ out2, int nrows)
{
    __shared__ char lds[65536];
    const int tid = threadIdx.x, lane = tid & 63, wv = tid >> 6;
    const int crow = lane & 15, kgrp = lane >> 4;
    const int r0 = blockIdx.x * 64, mrow0 = wv * 16;

    {   // prolog: stage x + WA0
        bf16x8 pref[8];
        load_wpref(wtA, pref, tid);
        stage_x64(x, lds, r0, nrows, tid);
        store_wpref(lds, pref, tid);
    }
    f32x4 acc[8], xe[8];
    #pragma unroll
    for (int n = 0; n < 8; ++n)
        #pragma unroll
        for (int rg = 0; rg < 4; ++rg) {
            const int gr = r0 + mrow0 + kgrp*4 + rg;
            xe[n][rg] = (gr < nrows) ? x[(size_t)gr*HD + n*16 + crow] : 0.f;
        }
    __syncthreads();

    // A1
    sb_pass1(lds, wtA + 16384, bA, tid, mrow0, crow, kgrp, acc);
    // A2: y1 = xe + silu(h @ WA1 + b), write into region1 (own rows), prefetch WB0
    {
        bf16x8 pref[8];
        load_wpref(wtB, pref, tid);
        mm_pass_lds(lds, 16384, bA + HD, mrow0, crow, kgrp, acc);
        #pragma unroll
        for (int n = 0; n < 8; ++n)
            #pragma unroll
            for (int rg = 0; rg < 4; ++rg)
                *(__bf16*)(lds + 16384 + swz(mrow0 + kgrp*4 + rg, (n*16 + crow)*2)) =
                    (__bf16)(xe[n][rg] + silu_f(acc[n][rg]));
        __syncthreads();
        store_wpref(lds, pref, tid);
        __syncthreads();
    }
    bounce_store(lds, 16384, out1, r0, nrows, tid);
    __syncthreads();          // bounce reads done before B1 overwrites region1

    // B1
    sb_pass1(lds, wtB + 16384, bB, tid, mrow0, crow, kgrp, acc);
    // B2: y2 into region0 (own rows), then bounce
    mm_pass_lds(lds, 16384, bB + HD, mrow0, crow, kgrp, acc);
    #pragma unroll
    for (int n = 0; n < 8; ++n)
        #pragma unroll
        for (int rg = 0; rg < 4; ++rg)
            *(__bf16*)(lds + swz(mrow0 + kgrp*4 + rg, (n*16 + crow)*2)) =
                (__bf16)(xe[n][rg] + silu_f(acc[n][rg]));
    __syncthreads();
    bounce_store(lds, 0, out2, r0, nrows, tid);
}

// ---- fused 4-block chain: y = post + R_D(R_C(mid ⊙ R_B(R_A(x)))), f32 carry in regs ----
__global__ __launch_bounds__(256) void chain4_kernel(
    const float* __restrict__ x, const __bf16* __restrict__ mid,
    const __bf16* __restrict__ wA, const float* __restrict__ bA,
    const __bf16* __restrict__ wB, const float* __restrict__ bB,
    const __bf16* __restrict__ wC, const float* __restrict__ bC,
    const __bf16* __restrict__ wD, const float* __restrict__ bD,
    const float* __restrict__ post, float* __restrict__ y, int nrows)
{
    __shared__ char lds[65536];
    const int tid = threadIdx.x, lane = tid & 63, wv = tid >> 6;
    const int crow = lane & 15, kgrp = lane >> 4;
    const int r0 = blockIdx.x * 64, mrow0 = wv * 16;

    {   // prolog
        bf16x8 pref[8];
        load_wpref(wA, pref, tid);
        stage_x64(x, lds, r0, nrows, tid);
        store_wpref(lds, pref, tid);
    }
    f32x4 carry[8], acc[8];
    #pragma unroll
    for (int n = 0; n < 8; ++n)
        #pragma unroll
        for (int rg = 0; rg < 4; ++rg) {
            const int gr = r0 + mrow0 + kgrp*4 + rg;
            carry[n][rg] = (gr < nrows) ? x[(size_t)gr*HD + n*16 + crow] : 0.f;
        }
    __syncthreads();

    // SB A
    sb_pass1(lds, wA + 16384, bA, tid, mrow0, crow, kgrp, acc);
    {
        bf16x8 pref[8];
        load_wpref(wB, pref, tid);
        mm_pass_lds(lds, 16384, bA + HD, mrow0, crow, kgrp, acc);
        #pragma unroll
        for (int n = 0; n < 8; ++n)
            #pragma unroll
            for (int rg = 0; rg < 4; ++rg) carry[n][rg] += silu_f(acc[n][rg]);
        __syncthreads();
        store_wpref(lds, pref, tid);
        restage64(lds, carry, mrow0, crow, kgrp);
        __syncthreads();
    }
    // SB B (+ mid multiply)
    sb_pass1(lds, wB + 16384, bB, tid, mrow0, crow, kgrp, acc);
    {
        bf16x8 pref[8];
        load_wpref(wC, pref, tid);
        mm_pass_lds(lds, 16384, bB + HD, mrow0, crow, kgrp, acc);
        #pragma unroll
        for (int n = 0; n < 8; ++n)
            #pragma unroll
            for (int rg = 0; rg < 4; ++rg) {
                const int gr = r0 + mrow0 + kgrp*4 + rg;
                const float m = (gr < nrows) ? (float)mid[(size_t)gr*HD + n*16 + crow] : 0.f;
                carry[n][rg] = (carry[n][rg] + silu_f(acc[n][rg])) * m;
            }
        __syncthreads();
        store_wpref(lds, pref, tid);
        restage64(lds, carry, mrow0, crow, kgrp);
        __syncthreads();
    }
    // SB C
    sb_pass1(lds, wC + 16384, bC, tid, mrow0, crow, kgrp, acc);
    {
        bf16x8 pref[8];
        load_wpref(wD, pref, tid);
        mm_pass_lds(lds, 16384, bC + HD, mrow0, crow, kgrp, acc);
        #pragma unroll
        for (int n = 0; n < 8; ++n)
            #pragma unroll
            for (int rg = 0; rg < 4; ++rg) carry[n][rg] += silu_f(acc[n][rg]);
        __syncthreads();
        store_wpref(lds, pref, tid);
        restage64(lds, carry, mrow0, crow, kgrp);
        __syncthreads();
    }
    // SB D + epilogue
    sb_pass1(lds, wD + 16384, bD, tid, mrow0, crow, kgrp, acc);
    mm_pass_lds(lds, 16384, bD + HD, mrow0, crow, kgrp, acc);
    #pragma unroll
    for (int n = 0; n < 8; ++n)
        #pragma unroll
        for (int rg = 0; rg < 4; ++rg) {
            const int gr = r0 + mrow0 + kgrp*4 + rg;
            if (gr < nrows) {
                const int cc = n*16 + crow;
                y[(size_t)gr*HD + cc] = carry[n][rg] + silu_f(acc[n][rg]) + post[(size_t)gr*HD + cc];
            }
        }
}

// ---- fused 3-block graph chain: out = R_C(R_B(R_A(x))) ----
__global__ __launch_bounds__(256) void chain3_kernel(
    const float* __restrict__ x,
    const __bf16* __restrict__ wA, const float* __restrict__ bA,
    const __bf16* __restrict__ wB, const float* __restrict__ bB,
    const __bf16* __restrict__ wC, const float* __restrict__ bC,
    float* __restrict__ y, int nrows)
{
    __shared__ char lds[65536];
    const int tid = threadIdx.x, lane = tid & 63, wv = tid >> 6;
    const int crow = lane & 15, kgrp = lane >> 4;
    const int r0 = blockIdx.x * 64, mrow0 = wv * 16;

    {
        bf16x8 pref[8];
        load_wpref(wA, pref, tid);
        stage_x64(x, lds, r0, nrows, tid);
        store_wpref(lds, pref, tid);
    }
    f32x4 carry[8], acc[8];
    #pragma unroll
    for (int n = 0; n < 8; ++n)
        #pragma unroll
        for (int rg = 0; rg < 4; ++rg) {
            const int gr = r0 + mrow0 + kgrp*4 + rg;
            carry[n][rg] = (gr < nrows) ? x[(size_t)gr*HD + n*16 + crow] : 0.f;
        }
    __syncthreads();

    sb_pass1(lds, wA + 16384, bA, tid, mrow0, crow, kgrp, acc);
    {
        bf16x8 pref[8];
        load_wpref(wB, pref, tid);
        mm_pass_lds(lds, 16384, bA + HD, mrow0, crow, kgrp, acc);
        #pragma unroll
        for (int n = 0; n < 8; ++n)
            #pragma unroll
            for (int rg = 0; rg < 4; ++rg) carry[n][rg] += silu_f(acc[n][rg]);
        __syncthreads();
        store_wpref(lds, pref, tid);
        restage64(lds, carry, mrow0, crow, kgrp);
        __syncthreads();
    }
    sb_pass1(lds, wB + 16384, bB, tid, mrow0, crow, kgrp, acc);
    {
        bf16x8 pref[8];
        load_wpref(wC, pref, tid);
        mm_pass_lds(lds, 16384, bB + HD, mrow0, crow, kgrp, acc);
        #pragma unroll
        for (int n = 0; n < 8; ++n)
            #pragma unroll
            for (int rg = 0; rg < 4; ++rg) carry[n][rg] += silu_f(acc[n][rg]);
        __syncthreads();
        store_wpref(lds, pref, tid);
        restage64(lds, carry, mrow0, crow, kgrp);
        __syncthreads();
    }
    sb_pass1(lds, wC + 16384, bC, tid, mrow0, crow, kgrp, acc);
    mm_pass_lds(lds, 16384, bC + HD, mrow0, crow, kgrp, acc);
    #pragma unroll
    for (int n = 0; n < 8; ++n)
        #pragma unroll
        for (int rg = 0; rg < 4; ++rg) {
            const int gr = r0 + mrow0 + kgrp*4 + rg;
            if (gr < nrows)
                y[(size_t)gr*HD + n*16 + crow] = carry[n][rg] + silu_f(acc[n][rg]);
        }
}

// ---- CSR build ----
__global__ __launch_bounds__(256) void hist_kernel(const int* __restrict__ erow, int* __restrict__ cnt, int E) {
    int i = blockIdx.x * blockDim.x + threadIdx.x;
    const int stride = gridDim.x * blockDim.x;
    for (; i < E; i += stride) atomicAdd(&cnt[erow[i]], 1);
}

__global__ __launch_bounds__(256) void scan1_kernel(const int* __restrict__ cnt, int* __restrict__ part, int n) {
    __shared__ int red[256];
    const int base = blockIdx.x * 1024;
    int s = 0;
    for (int i = threadIdx.x; i < 1024; i += 256) {
        const int idx = base + i;
        s += (idx < n) ? cnt[idx] : 0;
    }
    red[threadIdx.x] = s; __syncthreads();
    for (int o = 128; o > 0; o >>= 1) {
        if (threadIdx.x < o) red[threadIdx.x] += red[threadIdx.x + o];
        __syncthreads();
    }
    if (threadIdx.x == 0) part[blockIdx.x] = red[0];
}

__global__ __launch_bounds__(256) void scan2_kernel(int* __restrict__ part, int nb,
                                                    int* __restrict__ rowptr, int n) {
    __shared__ int sh[257];
    const int tid = threadIdx.x;
    int a[4]; int s = 0;
    #pragma unroll
    for (int q = 0; q < 4; ++q) {
        const int i = tid*4 + q;
        a[q] = (i < nb) ? part[i] : 0;
        s += a[q];
    }
    sh[tid + 1] = s; __syncthreads();
    if (tid == 0) {
        sh[0] = 0;
        int run = 0;
        for (int i = 1; i <= 256; ++i) { run += sh[i]; sh[i] = run; }
    }
    __syncthreads();
    int off = sh[tid];
    #pragma unroll
    for (int q = 0; q < 4; ++q) {
        const int i = tid*4 + q;
        if (i < nb) part[i] = off;
        off += a[q];
    }
    if (tid == 255) rowptr[n] = off;
}

__global__ __launch_bounds__(256) void scan3_kernel(const int* __restrict__ cnt, const int* __restrict__ part,
                                                    int* __restrict__ rowptr, int n) {
    __shared__ int sc[257];
    const int base = blockIdx.x * 1024;
    const int i0 = base + threadIdx.x * 4;
    int v[4]; int s = 0;
    #pragma unroll
    for (int q = 0; q < 4; ++q) {
        const int idx = i0 + q;
        v[q] = (idx < n) ? cnt[idx] : 0;
        s += v[q];
    }
    sc[threadIdx.x + 1] = s; __syncthreads();
    if (threadIdx.x == 0) {
        int run = 0;
        for (int i = 0; i < 256; ++i) { const int t = sc[i + 1]; sc[i + 1] = run; run += t; }
    }
    __syncthreads();
    int off = part[blockIdx.x] + sc[threadIdx.x + 1];
    #pragma unroll
    for (int q = 0; q < 4; ++q) {
        const int idx = i0 + q;
        if (idx < n) rowptr[idx] = off;
        off += v[q];
    }
}

// scatter + reorder fused: csr_col[p] = ecol[i], csr_ef[p] = fp16(ef[i] * cs[i])
__global__ __launch_bounds__(256) void scatter_reorder_kernel(
    const int* __restrict__ erow, const int* __restrict__ ecol,
    const float* __restrict__ ef, const float* __restrict__ cs,
    const int* __restrict__ rowptr, int* __restrict__ cursor,
    int* __restrict__ csr_col, _Float16* __restrict__ csr_ef, int E)
{
    int i = blockIdx.x * blockDim.x + threadIdx.x;
    const int stride = gridDim.x * blockDim.x;
    for (; i < E; i += stride) {
        const int r = erow[i];
        const int p = rowptr[r] + atomicAdd(&cursor[r], 1);
        csr_col[p] = ecol[i];
        const float c = cs[i];
        const float4* ep = (const float4*)(ef + (size_t)i * 16);
        const float4 e0 = ep[0], e1 = ep[1], e2 = ep[2], e3 = ep[3];
        h8 v0, v1;
        v0[0]=(_Float16)(e0.x*c); v0[1]=(_Float16)(e0.y*c); v0[2]=(_Float16)(e0.z*c); v0[3]=(_Float16)(e0.w*c);
        v0[4]=(_Float16)(e1.x*c); v0[5]=(_Float16)(e1.y*c); v0[6]=(_Float16)(e1.z*c); v0[7]=(_Float16)(e1.w*c);
        v1[0]=(_Float16)(e2.x*c); v1[1]=(_Float16)(e2.y*c); v1[2]=(_Float16)(e2.z*c); v1[3]=(_Float16)(e2.w*c);
        v1[4]=(_Float16)(e3.x*c); v1[5]=(_Float16)(e3.y*c); v1[6]=(_Float16)(e3.z*c); v1[7]=(_Float16)(e3.w*c);
        h8* dst = (h8*)(csr_ef + (size_t)p * 16);
        dst[0] = v0; dst[1] = v1;
    }
}

// elin f32 [16][128] -> fp16 (per layer)
__global__ __launch_bounds__(256) void elin16_kernel(const float* __restrict__ elin,
                                                     _Float16* __restrict__ out, int total) {
    const int i = blockIdx.x * 256 + threadIdx.x;
    if (i < total) out[i] = (_Float16)elin[i];
}

// ---- CSR gather conv: conv[v,j] = Cn[v] * Σ_t sdst[col_t, j] * (csr_ef[t] @ w[:,j]) ----
__global__ __launch_bounds__(256) void conv_kernel(
    const _Float16* __restrict__ csr_ef, const int* __restrict__ csr_col,
    const _Float16* __restrict__ elin16, const int* __restrict__ rowptr,
    const __bf16* __restrict__ sdst, const float* __restrict__ Cn,
    float* __restrict__ conv, int nnodes)
{
    const int half = threadIdx.x >> 7;
    const int j = threadIdx.x & 127;
    const int v0 = blockIdx.x * 8 + half * 4;
    h2 w2[8];
    #pragma unroll
    for (int k = 0; k < 8; ++k) {
        w2[k][0] = elin16[(2*k)   * HD + j];
        w2[k][1] = elin16[(2*k+1) * HD + j];
    }
    const int vend = (v0 + 4 < nnodes) ? v0 + 4 : nnodes;
    for (int v = v0; v < vend; ++v) {
        const int beg = rowptr[v], end = rowptr[v + 1];
        float acc = 0.f;
        int t = beg;
        for (; t + 2 <= end; t += 2) {
            const int c0 = csr_col[t], c1 = csr_col[t + 1];
            const h8* ep = (const h8*)(csr_ef + (size_t)t * 16);
            const h8 a0 = ep[0], a1 = ep[1], b0 = ep[2], b1 = ep[3];
            const float s0 = (float)sdst[(size_t)c0 * HD + j];
            const float s1 = (float)sdst[(size_t)c1 * HD + j];
            float f0 = 0.f, f1 = 0.f;
            #pragma unroll
            for (int k = 0; k < 4; ++k) {
                h2 p = {a0[2*k], a0[2*k+1]};
                f0 = fdot2f(p, w2[k], f0);
            }
            #pragma unroll
            for (int k = 0; k < 4; ++k) {
                h2 p = {a1[2*k], a1[2*k+1]};
                f0 = fdot2f(p, w2[4 + k], f0);
            }
            #pragma unroll
            for (int k = 0; k < 4; ++k) {
                h2 p = {b0[2*k], b0[2*k+1]};
                f1 = fdot2f(p, w2[k], f1);
            }
            #pragma unroll
            for (int k = 0; k < 4; ++k) {
                h2 p = {b1[2*k], b1[2*k+1]};
                f1 = fdot2f(p, w2[4 + k], f1);
            }
            acc = fmaf(s0, f0, acc);
            acc = fmaf(s1, f1, acc);
        }
        if (t < end) {
            const int c0 = csr_col[t];
            const h8* ep = (const h8*)(csr_ef + (size_t)t * 16);
            const h8 a0 = ep[0], a1 = ep[1];
            const float s0 = (float)sdst[(size_t)c0 * HD + j];
            float f0 = 0.f;
            #pragma unroll
            for (int k = 0; k < 4; ++k) {
                h2 p = {a0[2*k], a0[2*k+1]};
                f0 = fdot2f(p, w2[k], f0);
            }
            #pragma unroll
            for (int k = 0; k < 4; ++k) {
                h2 p = {a1[2*k], a1[2*k+1]};
                f0 = fdot2f(p, w2[4 + k], f0);
            }
            acc = fmaf(s0, f0, acc);
        }
        conv[(size_t)v * HD + j] = acc * Cn[v];
    }
}

// sorted segment-sum pooling: 256 thr = 8 row-slots x 32 col-quads; per-thread running acc
__global__ __launch_bounds__(256) void pool_kernel(
    const float* __restrict__ s, const int* __restrict__ bidx,
    float* __restrict__ g, int n)
{
    const int slot = threadIdx.x >> 5;
    const int jc   = (threadIdx.x & 31) * 4;
    const int base = blockIdx.x * 256;
    if (base >= n) return;
    const int end = (base + 256 < n) ? base + 256 : n;
    float4 acc = {0,0,0,0};
    int cur = -1;
    for (int i = base + slot; i < end; i += 8) {
        const int b = bidx[i];
        if (b != cur) {
            if (cur >= 0) {
                atomicAdd(g + (size_t)cur*HD + jc + 0, acc.x);
                atomicAdd(g + (size_t)cur*HD + jc + 1, acc.y);
                atomicAdd(g + (size_t)cur*HD + jc + 2, acc.z);
                atomicAdd(g + (size_t)cur*HD + jc + 3, acc.w);
            }
            acc = {0,0,0,0};
            cur = b;
        }
        const float4 v = *(const float4*)(s + (size_t)i*HD + jc);
        acc.x += v.x; acc.y += v.y; acc.z += v.z; acc.w += v.w;
    }
    if (cur >= 0) {
        atomicAdd(g + (size_t)cur*HD + jc + 0, acc.x);
        atomicAdd(g + (size_t)cur*HD + jc + 1, acc.y);
        atomicAdd(g + (size_t)cur*HD + jc + 2, acc.z);
        atomicAdd(g + (size_t)cur*HD + jc + 3, acc.w);
    }
}

// wt[mat][j][k] = (bf16) W[mat][k][j]
__global__ __launch_bounds__(256) void convw_kernel(const float* __restrict__ W, __bf16* __restrict__ wt, int total) {
    const int idx = blockIdx.x * 256 + threadIdx.x;
    if (idx >= total) return;
    const int mat = idx >> 14;
    const int rem = idx & 16383;
    const int jj = rem >> 7, kk = rem & 127;
    wt[idx] = (__bf16)W[(size_t)mat * 16384 + kk * HD + jj];
}

extern "C" void kernel_launch(void* const* d_in, const int* in_sizes, int n_in,
                              void* d_out, int out_size, void* d_ws, size_t ws_size,
                              hipStream_t stream) {
    const float* scalar = (const float*)d_in[0];
    const float* ef     = (const float*)d_in[1];
    const int*   eidx   = (const int*)  d_in[2];
    const float* Cn     = (const float*)d_in[3];
    const float* cs     = (const float*)d_in[4];
    const int*   bidx   = (const int*)  d_in[5];
    const float* resW   = (const float*)d_in[6];
    const float* resB   = (const float*)d_in[7];
    const float* elin   = (const float*)d_in[8];

    const int N      = in_sizes[0] / HD;
    const int E      = in_sizes[1] / 16;
    const int n_res  = in_sizes[7] / (2 * HD);
    const int layers = (n_res - 3) / 6;
    const int G      = out_size / HD;
    const size_t nfeat = (size_t)N * HD;

    char* p = (char*)d_ws;
    auto alloc = [&](size_t bytes) { char* q = p; p += (bytes + 255) & ~(size_t)255; return q; };
    float*    A      = (float*)alloc(nfeat * 4);
    float*    Dc     = (float*)alloc(nfeat * 4);
    __bf16*   Bs16   = (__bf16*)alloc(nfeat * 2);
    __bf16*   Cs16   = (__bf16*)alloc(nfeat * 2);
    __bf16*   wt     = (__bf16*)alloc((size_t)n_res * 2 * 16384 * 2);
    float*    graph  = (float*)alloc((size_t)G * HD * 4);
    int*      rowptr = (int*)alloc((size_t)(N + 1) * 4);
    int*      rowcnt = (int*)alloc((size_t)N * 4);
    int*      csr_col= (int*)alloc((size_t)E * 4);
    _Float16* csr_ef = (_Float16*)alloc((size_t)E * 16 * 2);
    _Float16* elin16 = (_Float16*)alloc((size_t)layers * 16 * HD * 2);
    int*      part   = (int*)alloc(1024 * 4);

    const int* erow = eidx;
    const int* ecol = eidx + E;

    const int totW = n_res * 2 * 16384;
    convw_kernel<<<(totW + 255) / 256, 256, 0, stream>>>(resW, wt, totW);
    const int totE = layers * 16 * HD;
    elin16_kernel<<<(totE + 255) / 256, 256, 0, stream>>>(elin, elin16, totE);

    const int nchunks = (N + 1023) / 1024;
    hipMemsetAsync(rowcnt, 0, (size_t)N * 4, stream);
    hist_kernel<<<1024, 256, 0, stream>>>(erow, rowcnt, E);
    scan1_kernel<<<nchunks, 256, 0, stream>>>(rowcnt, part, N);
    scan2_kernel<<<1, 256, 0, stream>>>(part, nchunks, rowptr, N);
    scan3_kernel<<<nchunks, 256, 0, stream>>>(rowcnt, part, rowptr, N);
    hipMemsetAsync(rowcnt, 0, (size_t)N * 4, stream);
    scatter_reorder_kernel<<<1024, 256, 0, stream>>>(erow, ecol, ef, cs, rowptr, rowcnt, csr_col, csr_ef, E);

    const int gridR = (N + 63) / 64;
    const float* cur = scalar;
    for (int i = 0; i < layers; ++i) {
        const int pb = 6 * i;
        resid_dual_kernel<<<gridR, 256, 0, stream>>>(
            cur,
            wt + (size_t)pb * 32768, resB + (size_t)pb * 256,
            wt + (size_t)(pb + 1) * 32768, resB + (size_t)(pb + 1) * 256,
            Bs16, Cs16, N);
        conv_kernel<<<(N + 7) / 8, 256, 0, stream>>>(
            csr_ef, csr_col, elin16 + (size_t)i * 16 * HD, rowptr, Cs16, Cn, Dc, N);
        chain4_kernel<<<gridR, 256, 0, stream>>>(
            Dc, Bs16,
            wt + (size_t)(pb + 2) * 32768, resB + (size_t)(pb + 2) * 256,
            wt + (size_t)(pb + 3) * 32768, resB + (size_t)(pb + 3) * 256,
            wt + (size_t)(pb + 4) * 32768, resB + (size_t)(pb + 4) * 256,
            wt + (size_t)(pb + 5) * 32768, resB + (size_t)(pb + 5) * 256,
            cur, A, N);
        cur = A;
    }

    hipMemsetAsync(graph, 0, (size_t)G * HD * 4, stream);
    pool_kernel<<<(N + 255) / 256, 256, 0, stream>>>(cur, bidx, graph, N);

    const int q = 6 * layers;
    const int gridG = (G + 63) / 64;
    chain3_kernel<<<gridG, 256, 0, stream>>>(
        graph,
        wt + (size_t)q * 32768, resB + (size_t)q * 256,
        wt + (size_t)(q + 1) * 32768, resB + (size_t)(q + 1) * 256,
        wt + (size_t)(q + 2) * 32768, resB + (size_t)(q + 2) * 256,
        (float*)d_out, G);
}

// Round 6
// 886.492 us; speedup vs baseline: 3.5219x; 1.5913x over previous
//
#include <hip/hip_runtime.h>
#include <hip/hip_bf16.h>
#include <cstdint>
#include <cstddef>

#define HD 128
#define WOFF 32768   // W tile region in LDS

typedef __bf16    bf16x8 __attribute__((ext_vector_type(8)));
typedef float     f32x4  __attribute__((ext_vector_type(4)));
typedef _Float16  h2     __attribute__((ext_vector_type(2)));
typedef _Float16  h8     __attribute__((ext_vector_type(8)));

#if defined(__has_builtin)
#if __has_builtin(__builtin_amdgcn_fdot2)
#define HAVE_FDOT2 1
#endif
#endif

__device__ __forceinline__ float fdot2f(h2 a, h2 b, float c) {
#ifdef HAVE_FDOT2
    return __builtin_amdgcn_fdot2(a, b, c, false);
#else
    return c + (float)a[0]*(float)b[0] + (float)a[1]*(float)b[1];
#endif
}

// Swizzled LDS byte offset: row r (256B rows), byte-in-row b. chunk ^= (r&7) kills
// the stride-256B bank conflict on column-slice ds_read_b128.
__device__ __forceinline__ int swz(int r, int byteInRow) {
    int chunk = (byteInRow >> 4) ^ (r & 7);
    return r * 256 + (chunk << 4) + (byteInRow & 15);
}

__device__ __forceinline__ float silu_f(float v) { return v / (1.f + __expf(-v)); }

// ================== 512-thread residual building blocks ==================
// 8 waves: pair (wv>>1) owns rows (wv>>1)*16..+16; sub (wv&1) owns n-tiles nbase=sub*4..+4.
// LDS: [0,16K) region0, [16K,32K) region1, [32K,64K) Wbuf.

__device__ __forceinline__ void stage_x64(const float* __restrict__ x, char* lds,
                                          int r0, int nrows, int tid) {
    const int q = tid & 15;
    #pragma unroll
    for (int rr = 0; rr < 2; ++rr) {
        const int r  = (tid >> 4) + rr * 32;
        const int gr = r0 + r;
        float4 a = {0,0,0,0}, b = {0,0,0,0};
        if (gr < nrows) {
            const float4* p = (const float4*)(x + (size_t)gr * HD + q * 8);
            a = p[0]; b = p[1];
        }
        bf16x8 v;
        v[0]=(__bf16)a.x; v[1]=(__bf16)a.y; v[2]=(__bf16)a.z; v[3]=(__bf16)a.w;
        v[4]=(__bf16)b.x; v[5]=(__bf16)b.y; v[6]=(__bf16)b.z; v[7]=(__bf16)b.w;
        *(bf16x8*)(lds + swz(r, q * 16)) = v;
    }
}

__device__ __forceinline__ void load_wpref(const __bf16* __restrict__ w, bf16x8 pref[4], int tid) {
    #pragma unroll
    for (int i = 0; i < 4; ++i)
        pref[i] = *(const bf16x8*)(w + (size_t)(i * 512 + tid) * 8);
}
__device__ __forceinline__ void store_wpref(char* lds, const bf16x8 pref[4], int tid) {
    #pragma unroll
    for (int i = 0; i < 4; ++i) {
        const int l = i * 512 + tid;
        *(bf16x8*)(lds + WOFF + swz(l >> 4, (l & 15) * 16)) = pref[i];
    }
}

// acc[ni] = (region[src_off] @ Wbuf)[rows mrow0.., cols (nbase+ni)*16..] + bias
__device__ __forceinline__ void mm_pass_lds(const char* lds, int src_off,
                                            const float* __restrict__ bias,
                                            int mrow0, int nbase, int crow, int kgrp, f32x4 acc[4]) {
    bf16x8 afr[4];
    #pragma unroll
    for (int kk = 0; kk < 4; ++kk)
        afr[kk] = *(const bf16x8*)(lds + src_off + swz(mrow0 + crow, kk*64 + kgrp*16));
    #pragma unroll
    for (int ni = 0; ni < 4; ++ni) {
        const float bv = bias[(nbase + ni) * 16 + crow];
        f32x4 t = {bv, bv, bv, bv};
        acc[ni] = t;
    }
    #pragma unroll
    for (int ni = 0; ni < 4; ++ni) {
        #pragma unroll
        for (int kk = 0; kk < 4; ++kk) {
            const bf16x8 bfr = *(const bf16x8*)(lds + WOFF + swz((nbase+ni)*16 + crow, kk*64 + kgrp*16));
            acc[ni] = __builtin_amdgcn_mfma_f32_16x16x32_bf16(afr[kk], bfr, acc[ni], 0, 0, 0);
        }
    }
}

__device__ __forceinline__ void write_h64(char* lds, int off, const f32x4 acc[4],
                                          int mrow0, int nbase, int crow, int kgrp) {
    #pragma unroll
    for (int ni = 0; ni < 4; ++ni)
        #pragma unroll
        for (int rg = 0; rg < 4; ++rg)
            *(__bf16*)(lds + off + swz(mrow0 + kgrp*4 + rg, ((nbase+ni)*16 + crow)*2)) =
                (__bf16)silu_f(acc[ni][rg]);
}

__device__ __forceinline__ void restage64(char* lds, const f32x4 carry[4],
                                          int mrow0, int nbase, int crow, int kgrp) {
    #pragma unroll
    for (int ni = 0; ni < 4; ++ni)
        #pragma unroll
        for (int rg = 0; rg < 4; ++rg)
            *(__bf16*)(lds + swz(mrow0 + kgrp*4 + rg, ((nbase+ni)*16 + crow)*2)) =
                (__bf16)carry[ni][rg];
}

// pass1 of a residual sub-block: h = silu(region0 @ Wbuf + b); then stage w1next into Wbuf
__device__ __forceinline__ void sb_pass1(char* lds, const __bf16* __restrict__ w1next,
                                         const float* __restrict__ bias,
                                         int tid, int mrow0, int nbase, int crow, int kgrp, f32x4 acc[4]) {
    bf16x8 pref[4];
    load_wpref(w1next, pref, tid);
    mm_pass_lds(lds, 0, bias, mrow0, nbase, crow, kgrp, acc);
    write_h64(lds, 16384, acc, mrow0, nbase, crow, kgrp);
    __syncthreads();
    store_wpref(lds, pref, tid);
    __syncthreads();
}

__device__ __forceinline__ void bounce_store(const char* lds, int off, __bf16* __restrict__ out,
                                             int r0, int nrows, int tid) {
    const int q = tid & 15;
    #pragma unroll
    for (int rr = 0; rr < 2; ++rr) {
        const int r = (tid >> 4) + rr * 32, gr = r0 + r;
        if (gr < nrows)
            *(bf16x8*)(out + (size_t)gr * HD + q * 8) = *(const bf16x8*)(lds + off + swz(r, q * 16));
    }
}

// ---- dual residual: out1 = bf16(x + mlpA(x)), out2 = bf16(x + mlpB(x)) ----
__global__ __launch_bounds__(512) void resid_dual_kernel(
    const float* __restrict__ x,
    const __bf16* __restrict__ wtA, const float* __restrict__ bA,
    const __bf16* __restrict__ wtB, const float* __restrict__ bB,
    __bf16* __restrict__ out1, __bf16* __restrict__ out2, int nrows)
{
    __shared__ char lds[65536];
    const int tid = threadIdx.x, lane = tid & 63, wv = tid >> 6;
    const int crow = lane & 15, kgrp = lane >> 4;
    const int r0 = blockIdx.x * 64;
    const int mrow0 = (wv >> 1) * 16, nbase = (wv & 1) * 4;

    {
        bf16x8 pref[4];
        load_wpref(wtA, pref, tid);
        stage_x64(x, lds, r0, nrows, tid);
        store_wpref(lds, pref, tid);
    }
    f32x4 acc[4], xe[4];
    #pragma unroll
    for (int ni = 0; ni < 4; ++ni)
        #pragma unroll
        for (int rg = 0; rg < 4; ++rg) {
            const int gr = r0 + mrow0 + kgrp*4 + rg;
            xe[ni][rg] = (gr < nrows) ? x[(size_t)gr*HD + (nbase+ni)*16 + crow] : 0.f;
        }
    __syncthreads();

    // A1
    sb_pass1(lds, wtA + 16384, bA, tid, mrow0, nbase, crow, kgrp, acc);
    // A2: y1 into region1 (own rows/cols), prefetch WB0
    {
        bf16x8 pref[4];
        load_wpref(wtB, pref, tid);
        mm_pass_lds(lds, 16384, bA + HD, mrow0, nbase, crow, kgrp, acc);
        #pragma unroll
        for (int ni = 0; ni < 4; ++ni)
            #pragma unroll
            for (int rg = 0; rg < 4; ++rg)
                *(__bf16*)(lds + 16384 + swz(mrow0 + kgrp*4 + rg, ((nbase+ni)*16 + crow)*2)) =
                    (__bf16)(xe[ni][rg] + silu_f(acc[ni][rg]));
        __syncthreads();
        store_wpref(lds, pref, tid);
        __syncthreads();
    }
    bounce_store(lds, 16384, out1, r0, nrows, tid);
    __syncthreads();          // bounce reads done before B1 overwrites region1

    // B1
    sb_pass1(lds, wtB + 16384, bB, tid, mrow0, nbase, crow, kgrp, acc);
    // B2: y2 into region0, bounce
    mm_pass_lds(lds, 16384, bB + HD, mrow0, nbase, crow, kgrp, acc);
    #pragma unroll
    for (int ni = 0; ni < 4; ++ni)
        #pragma unroll
        for (int rg = 0; rg < 4; ++rg)
            *(__bf16*)(lds + swz(mrow0 + kgrp*4 + rg, ((nbase+ni)*16 + crow)*2)) =
                (__bf16)(xe[ni][rg] + silu_f(acc[ni][rg]));
    __syncthreads();
    bounce_store(lds, 0, out2, r0, nrows, tid);
}

// ---- fused 4-block chain: y = post + R_D(R_C(mid ⊙ R_B(R_A(x)))), f32 carry in regs ----
__global__ __launch_bounds__(512) void chain4_kernel(
    const float* __restrict__ x, const __bf16* __restrict__ mid,
    const __bf16* __restrict__ wA, const float* __restrict__ bA,
    const __bf16* __restrict__ wB, const float* __restrict__ bB,
    const __bf16* __restrict__ wC, const float* __restrict__ bC,
    const __bf16* __restrict__ wD, const float* __restrict__ bD,
    const float* __restrict__ post, float* __restrict__ y, int nrows)
{
    __shared__ char lds[65536];
    const int tid = threadIdx.x, lane = tid & 63, wv = tid >> 6;
    const int crow = lane & 15, kgrp = lane >> 4;
    const int r0 = blockIdx.x * 64;
    const int mrow0 = (wv >> 1) * 16, nbase = (wv & 1) * 4;

    {
        bf16x8 pref[4];
        load_wpref(wA, pref, tid);
        stage_x64(x, lds, r0, nrows, tid);
        store_wpref(lds, pref, tid);
    }
    f32x4 carry[4], acc[4];
    #pragma unroll
    for (int ni = 0; ni < 4; ++ni)
        #pragma unroll
        for (int rg = 0; rg < 4; ++rg) {
            const int gr = r0 + mrow0 + kgrp*4 + rg;
            carry[ni][rg] = (gr < nrows) ? x[(size_t)gr*HD + (nbase+ni)*16 + crow] : 0.f;
        }
    __syncthreads();

    // SB A
    sb_pass1(lds, wA + 16384, bA, tid, mrow0, nbase, crow, kgrp, acc);
    {
        bf16x8 pref[4];
        load_wpref(wB, pref, tid);
        mm_pass_lds(lds, 16384, bA + HD, mrow0, nbase, crow, kgrp, acc);
        #pragma unroll
        for (int ni = 0; ni < 4; ++ni)
            #pragma unroll
            for (int rg = 0; rg < 4; ++rg) carry[ni][rg] += silu_f(acc[ni][rg]);
        __syncthreads();
        store_wpref(lds, pref, tid);
        restage64(lds, carry, mrow0, nbase, crow, kgrp);
        __syncthreads();
    }
    // SB B (+ mid multiply)
    sb_pass1(lds, wB + 16384, bB, tid, mrow0, nbase, crow, kgrp, acc);
    {
        bf16x8 pref[4];
        load_wpref(wC, pref, tid);
        mm_pass_lds(lds, 16384, bB + HD, mrow0, nbase, crow, kgrp, acc);
        #pragma unroll
        for (int ni = 0; ni < 4; ++ni)
            #pragma unroll
            for (int rg = 0; rg < 4; ++rg) {
                const int gr = r0 + mrow0 + kgrp*4 + rg;
                const float m = (gr < nrows) ? (float)mid[(size_t)gr*HD + (nbase+ni)*16 + crow] : 0.f;
                carry[ni][rg] = (carry[ni][rg] + silu_f(acc[ni][rg])) * m;
            }
        __syncthreads();
        store_wpref(lds, pref, tid);
        restage64(lds, carry, mrow0, nbase, crow, kgrp);
        __syncthreads();
    }
    // SB C
    sb_pass1(lds, wC + 16384, bC, tid, mrow0, nbase, crow, kgrp, acc);
    {
        bf16x8 pref[4];
        load_wpref(wD, pref, tid);
        mm_pass_lds(lds, 16384, bC + HD, mrow0, nbase, crow, kgrp, acc);
        #pragma unroll
        for (int ni = 0; ni < 4; ++ni)
            #pragma unroll
            for (int rg = 0; rg < 4; ++rg) carry[ni][rg] += silu_f(acc[ni][rg]);
        __syncthreads();
        store_wpref(lds, pref, tid);
        restage64(lds, carry, mrow0, nbase, crow, kgrp);
        __syncthreads();
    }
    // SB D + epilogue
    sb_pass1(lds, wD + 16384, bD, tid, mrow0, nbase, crow, kgrp, acc);
    mm_pass_lds(lds, 16384, bD + HD, mrow0, nbase, crow, kgrp, acc);
    #pragma unroll
    for (int ni = 0; ni < 4; ++ni)
        #pragma unroll
        for (int rg = 0; rg < 4; ++rg) {
            const int gr = r0 + mrow0 + kgrp*4 + rg;
            if (gr < nrows) {
                const int cc = (nbase+ni)*16 + crow;
                y[(size_t)gr*HD + cc] = carry[ni][rg] + silu_f(acc[ni][rg]) + post[(size_t)gr*HD + cc];
            }
        }
}

// ---- fused 3-block graph chain: out = R_C(R_B(R_A(x))) ----
__global__ __launch_bounds__(512) void chain3_kernel(
    const float* __restrict__ x,
    const __bf16* __restrict__ wA, const float* __restrict__ bA,
    const __bf16* __restrict__ wB, const float* __restrict__ bB,
    const __bf16* __restrict__ wC, const float* __restrict__ bC,
    float* __restrict__ y, int nrows)
{
    __shared__ char lds[65536];
    const int tid = threadIdx.x, lane = tid & 63, wv = tid >> 6;
    const int crow = lane & 15, kgrp = lane >> 4;
    const int r0 = blockIdx.x * 64;
    const int mrow0 = (wv >> 1) * 16, nbase = (wv & 1) * 4;

    {
        bf16x8 pref[4];
        load_wpref(wA, pref, tid);
        stage_x64(x, lds, r0, nrows, tid);
        store_wpref(lds, pref, tid);
    }
    f32x4 carry[4], acc[4];
    #pragma unroll
    for (int ni = 0; ni < 4; ++ni)
        #pragma unroll
        for (int rg = 0; rg < 4; ++rg) {
            const int gr = r0 + mrow0 + kgrp*4 + rg;
            carry[ni][rg] = (gr < nrows) ? x[(size_t)gr*HD + (nbase+ni)*16 + crow] : 0.f;
        }
    __syncthreads();

    sb_pass1(lds, wA + 16384, bA, tid, mrow0, nbase, crow, kgrp, acc);
    {
        bf16x8 pref[4];
        load_wpref(wB, pref, tid);
        mm_pass_lds(lds, 16384, bA + HD, mrow0, nbase, crow, kgrp, acc);
        #pragma unroll
        for (int ni = 0; ni < 4; ++ni)
            #pragma unroll
            for (int rg = 0; rg < 4; ++rg) carry[ni][rg] += silu_f(acc[ni][rg]);
        __syncthreads();
        store_wpref(lds, pref, tid);
        restage64(lds, carry, mrow0, nbase, crow, kgrp);
        __syncthreads();
    }
    sb_pass1(lds, wB + 16384, bB, tid, mrow0, nbase, crow, kgrp, acc);
    {
        bf16x8 pref[4];
        load_wpref(wC, pref, tid);
        mm_pass_lds(lds, 16384, bB + HD, mrow0, nbase, crow, kgrp, acc);
        #pragma unroll
        for (int ni = 0; ni < 4; ++ni)
            #pragma unroll
            for (int rg = 0; rg < 4; ++rg) carry[ni][rg] += silu_f(acc[ni][rg]);
        __syncthreads();
        store_wpref(lds, pref, tid);
        restage64(lds, carry, mrow0, nbase, crow, kgrp);
        __syncthreads();
    }
    sb_pass1(lds, wC + 16384, bC, tid, mrow0, nbase, crow, kgrp, acc);
    mm_pass_lds(lds, 16384, bC + HD, mrow0, nbase, crow, kgrp, acc);
    #pragma unroll
    for (int ni = 0; ni < 4; ++ni)
        #pragma unroll
        for (int rg = 0; rg < 4; ++rg) {
            const int gr = r0 + mrow0 + kgrp*4 + rg;
            if (gr < nrows)
                y[(size_t)gr*HD + (nbase+ni)*16 + crow] = carry[ni][rg] + silu_f(acc[ni][rg]);
        }
}

// ---- CSR build ----
__global__ __launch_bounds__(256) void hist_kernel(const int* __restrict__ erow, int* __restrict__ cnt, int E) {
    int i = blockIdx.x * blockDim.x + threadIdx.x;
    const int stride = gridDim.x * blockDim.x;
    for (; i < E; i += stride) atomicAdd(&cnt[erow[i]], 1);
}

__global__ __launch_bounds__(256) void scan1_kernel(const int* __restrict__ cnt, int* __restrict__ part, int n) {
    __shared__ int red[256];
    const int base = blockIdx.x * 1024;
    int s = 0;
    for (int i = threadIdx.x; i < 1024; i += 256) {
        const int idx = base + i;
        s += (idx < n) ? cnt[idx] : 0;
    }
    red[threadIdx.x] = s; __syncthreads();
    for (int o = 128; o > 0; o >>= 1) {
        if (threadIdx.x < o) red[threadIdx.x] += red[threadIdx.x + o];
        __syncthreads();
    }
    if (threadIdx.x == 0) part[blockIdx.x] = red[0];
}

__global__ __launch_bounds__(256) void scan2_kernel(int* __restrict__ part, int nb,
                                                    int* __restrict__ rowptr, int n) {
    __shared__ int sh[257];
    const int tid = threadIdx.x;
    int a[4]; int s = 0;
    #pragma unroll
    for (int q = 0; q < 4; ++q) {
        const int i = tid*4 + q;
        a[q] = (i < nb) ? part[i] : 0;
        s += a[q];
    }
    sh[tid + 1] = s; __syncthreads();
    if (tid == 0) {
        sh[0] = 0;
        int run = 0;
        for (int i = 1; i <= 256; ++i) { run += sh[i]; sh[i] = run; }
    }
    __syncthreads();
    int off = sh[tid];
    #pragma unroll
    for (int q = 0; q < 4; ++q) {
        const int i = tid*4 + q;
        if (i < nb) part[i] = off;
        off += a[q];
    }
    if (tid == 255) rowptr[n] = off;
}

__global__ __launch_bounds__(256) void scan3_kernel(const int* __restrict__ cnt, const int* __restrict__ part,
                                                    int* __restrict__ rowptr, int n) {
    __shared__ int sc[257];
    const int base = blockIdx.x * 1024;
    const int i0 = base + threadIdx.x * 4;
    int v[4]; int s = 0;
    #pragma unroll
    for (int q = 0; q < 4; ++q) {
        const int idx = i0 + q;
        v[q] = (idx < n) ? cnt[idx] : 0;
        s += v[q];
    }
    sc[threadIdx.x + 1] = s; __syncthreads();
    if (threadIdx.x == 0) {
        int run = 0;
        for (int i = 0; i < 256; ++i) { const int t = sc[i + 1]; sc[i + 1] = run; run += t; }
    }
    __syncthreads();
    int off = part[blockIdx.x] + sc[threadIdx.x + 1];
    #pragma unroll
    for (int q = 0; q < 4; ++q) {
        const int idx = i0 + q;
        if (idx < n) rowptr[idx] = off;
        off += v[q];
    }
}

// scatter + reorder fused: csr_col[p] = ecol[i], csr_ef[p] = fp16(ef[i] * cs[i])
__global__ __launch_bounds__(256) void scatter_reorder_kernel(
    const int* __restrict__ erow, const int* __restrict__ ecol,
    const float* __restrict__ ef, const float* __restrict__ cs,
    const int* __restrict__ rowptr, int* __restrict__ cursor,
    int* __restrict__ csr_col, _Float16* __restrict__ csr_ef, int E)
{
    int i = blockIdx.x * blockDim.x + threadIdx.x;
    const int stride = gridDim.x * blockDim.x;
    for (; i < E; i += stride) {
        const int r = erow[i];
        const int p = rowptr[r] + atomicAdd(&cursor[r], 1);
        csr_col[p] = ecol[i];
        const float c = cs[i];
        const float4* ep = (const float4*)(ef + (size_t)i * 16);
        const float4 e0 = ep[0], e1 = ep[1], e2 = ep[2], e3 = ep[3];
        h8 v0, v1;
        v0[0]=(_Float16)(e0.x*c); v0[1]=(_Float16)(e0.y*c); v0[2]=(_Float16)(e0.z*c); v0[3]=(_Float16)(e0.w*c);
        v0[4]=(_Float16)(e1.x*c); v0[5]=(_Float16)(e1.y*c); v0[6]=(_Float16)(e1.z*c); v0[7]=(_Float16)(e1.w*c);
        v1[0]=(_Float16)(e2.x*c); v1[1]=(_Float16)(e2.y*c); v1[2]=(_Float16)(e2.z*c); v1[3]=(_Float16)(e2.w*c);
        v1[4]=(_Float16)(e3.x*c); v1[5]=(_Float16)(e3.y*c); v1[6]=(_Float16)(e3.z*c); v1[7]=(_Float16)(e3.w*c);
        h8* dst = (h8*)(csr_ef + (size_t)p * 16);
        dst[0] = v0; dst[1] = v1;
    }
}

// elin f32 [16][128] -> fp16 (per layer)
__global__ __launch_bounds__(256) void elin16_kernel(const float* __restrict__ elin,
                                                     _Float16* __restrict__ out, int total) {
    const int i = blockIdx.x * 256 + threadIdx.x;
    if (i < total) out[i] = (_Float16)elin[i];
}

__device__ __forceinline__ float bfu_lo(uint32_t u) { return __uint_as_float(u << 16); }
__device__ __forceinline__ float bfu_hi(uint32_t u) { return __uint_as_float(u & 0xffff0000u); }

__device__ __forceinline__ void edge_dot(const h8 a0, const h8 a1,
                                         const h2 w0[8], const h2 w1[8],
                                         float& f0, float& f1) {
    #pragma unroll
    for (int kk = 0; kk < 4; ++kk) {
        h2 p = {a0[2*kk], a0[2*kk+1]};
        f0 = fdot2f(p, w0[kk], f0);
        f1 = fdot2f(p, w1[kk], f1);
    }
    #pragma unroll
    for (int kk = 0; kk < 4; ++kk) {
        h2 p = {a1[2*kk], a1[2*kk+1]};
        f0 = fdot2f(p, w0[4+kk], f0);
        f1 = fdot2f(p, w1[4+kk], f1);
    }
}

// ---- CSR gather conv, wave-per-node: lane handles cols (2l, 2l+1) of its node's row ----
__global__ __launch_bounds__(256) void conv_kernel(
    const _Float16* __restrict__ csr_ef, const int* __restrict__ csr_col,
    const _Float16* __restrict__ elin16, const int* __restrict__ rowptr,
    const __bf16* __restrict__ sdst, const float* __restrict__ Cn,
    float* __restrict__ conv, int nnodes)
{
    const int wv   = __builtin_amdgcn_readfirstlane(threadIdx.x >> 6);
    const int lane = threadIdx.x & 63;
    const int v = blockIdx.x * 4 + wv;
    if (v >= nnodes) return;
    const int j0 = lane * 2;

    h2 w0[8], w1[8];
    #pragma unroll
    for (int kk = 0; kk < 8; ++kk) {
        w0[kk][0] = elin16[(2*kk)   * HD + j0];
        w0[kk][1] = elin16[(2*kk+1) * HD + j0];
        w1[kk][0] = elin16[(2*kk)   * HD + j0 + 1];
        w1[kk][1] = elin16[(2*kk+1) * HD + j0 + 1];
    }

    const uint16_t* sd = (const uint16_t*)sdst;
    const int beg = rowptr[v], end = rowptr[v + 1];
    float acc0 = 0.f, acc1 = 0.f;
    int t = beg;
    for (; t + 4 <= end; t += 4) {
        int c[4];
        #pragma unroll
        for (int q = 0; q < 4; ++q) c[q] = csr_col[t + q];
        uint32_t u[4];
        #pragma unroll
        for (int q = 0; q < 4; ++q)
            u[q] = *(const uint32_t*)(sd + (size_t)c[q] * HD + j0);
        #pragma unroll
        for (int q = 0; q < 4; ++q) {
            const h8* ep = (const h8*)(csr_ef + (size_t)(t + q) * 16);
            const h8 a0 = ep[0], a1 = ep[1];
            float f0 = 0.f, f1 = 0.f;
            edge_dot(a0, a1, w0, w1, f0, f1);
            acc0 = fmaf(bfu_lo(u[q]), f0, acc0);
            acc1 = fmaf(bfu_hi(u[q]), f1, acc1);
        }
    }
    for (; t < end; ++t) {
        const int c = csr_col[t];
        const uint32_t u = *(const uint32_t*)(sd + (size_t)c * HD + j0);
        const h8* ep = (const h8*)(csr_ef + (size_t)t * 16);
        const h8 a0 = ep[0], a1 = ep[1];
        float f0 = 0.f, f1 = 0.f;
        edge_dot(a0, a1, w0, w1, f0, f1);
        acc0 = fmaf(bfu_lo(u), f0, acc0);
        acc1 = fmaf(bfu_hi(u), f1, acc1);
    }
    const float cn = Cn[v];
    float2 out = {acc0 * cn, acc1 * cn};
    *(float2*)(conv + (size_t)v * HD + j0) = out;
}

// sorted segment-sum pooling: 256 thr = 8 row-slots x 32 col-quads; per-thread running acc
__global__ __launch_bounds__(256) void pool_kernel(
    const float* __restrict__ s, const int* __restrict__ bidx,
    float* __restrict__ g, int n)
{
    const int slot = threadIdx.x >> 5;
    const int jc   = (threadIdx.x & 31) * 4;
    const int base = blockIdx.x * 256;
    if (base >= n) return;
    const int end = (base + 256 < n) ? base + 256 : n;
    float4 acc = {0,0,0,0};
    int cur = -1;
    for (int i = base + slot; i < end; i += 8) {
        const int b = bidx[i];
        if (b != cur) {
            if (cur >= 0) {
                atomicAdd(g + (size_t)cur*HD + jc + 0, acc.x);
                atomicAdd(g + (size_t)cur*HD + jc + 1, acc.y);
                atomicAdd(g + (size_t)cur*HD + jc + 2, acc.z);
                atomicAdd(g + (size_t)cur*HD + jc + 3, acc.w);
            }
            acc = {0,0,0,0};
            cur = b;
        }
        const float4 v = *(const float4*)(s + (size_t)i*HD + jc);
        acc.x += v.x; acc.y += v.y; acc.z += v.z; acc.w += v.w;
    }
    if (cur >= 0) {
        atomicAdd(g + (size_t)cur*HD + jc + 0, acc.x);
        atomicAdd(g + (size_t)cur*HD + jc + 1, acc.y);
        atomicAdd(g + (size_t)cur*HD + jc + 2, acc.z);
        atomicAdd(g + (size_t)cur*HD + jc + 3, acc.w);
    }
}

// wt[mat][j][k] = (bf16) W[mat][k][j]
__global__ __launch_bounds__(256) void convw_kernel(const float* __restrict__ W, __bf16* __restrict__ wt, int total) {
    const int idx = blockIdx.x * 256 + threadIdx.x;
    if (idx >= total) return;
    const int mat = idx >> 14;
    const int rem = idx & 16383;
    const int jj = rem >> 7, kk = rem & 127;
    wt[idx] = (__bf16)W[(size_t)mat * 16384 + kk * HD + jj];
}

extern "C" void kernel_launch(void* const* d_in, const int* in_sizes, int n_in,
                              void* d_out, int out_size, void* d_ws, size_t ws_size,
                              hipStream_t stream) {
    const float* scalar = (const float*)d_in[0];
    const float* ef     = (const float*)d_in[1];
    const int*   eidx   = (const int*)  d_in[2];
    const float* Cn     = (const float*)d_in[3];
    const float* cs     = (const float*)d_in[4];
    const int*   bidx   = (const int*)  d_in[5];
    const float* resW   = (const float*)d_in[6];
    const float* resB   = (const float*)d_in[7];
    const float* elin   = (const float*)d_in[8];

    const int N      = in_sizes[0] / HD;
    const int E      = in_sizes[1] / 16;
    const int n_res  = in_sizes[7] / (2 * HD);
    const int layers = (n_res - 3) / 6;
    const int G      = out_size / HD;
    const size_t nfeat = (size_t)N * HD;

    char* p = (char*)d_ws;
    auto alloc = [&](size_t bytes) { char* q = p; p += (bytes + 255) & ~(size_t)255; return q; };
    float*    A      = (float*)alloc(nfeat * 4);
    float*    Dc     = (float*)alloc(nfeat * 4);
    __bf16*   Bs16   = (__bf16*)alloc(nfeat * 2);
    __bf16*   Cs16   = (__bf16*)alloc(nfeat * 2);
    __bf16*   wt     = (__bf16*)alloc((size_t)n_res * 2 * 16384 * 2);
    float*    graph  = (float*)alloc((size_t)G * HD * 4);
    int*      rowptr = (int*)alloc((size_t)(N + 1) * 4);
    int*      rowcnt = (int*)alloc((size_t)N * 4);
    int*      csr_col= (int*)alloc((size_t)E * 4);
    _Float16* csr_ef = (_Float16*)alloc((size_t)E * 16 * 2);
    _Float16* elin16 = (_Float16*)alloc((size_t)layers * 16 * HD * 2);
    int*      part   = (int*)alloc(1024 * 4);

    const int* erow = eidx;
    const int* ecol = eidx + E;

    const int totW = n_res * 2 * 16384;
    convw_kernel<<<(totW + 255) / 256, 256, 0, stream>>>(resW, wt, totW);
    const int totE = layers * 16 * HD;
    elin16_kernel<<<(totE + 255) / 256, 256, 0, stream>>>(elin, elin16, totE);

    const int nchunks = (N + 1023) / 1024;
    hipMemsetAsync(rowcnt, 0, (size_t)N * 4, stream);
    hist_kernel<<<1024, 256, 0, stream>>>(erow, rowcnt, E);
    scan1_kernel<<<nchunks, 256, 0, stream>>>(rowcnt, part, N);
    scan2_kernel<<<1, 256, 0, stream>>>(part, nchunks, rowptr, N);
    scan3_kernel<<<nchunks, 256, 0, stream>>>(rowcnt, part, rowptr, N);
    hipMemsetAsync(rowcnt, 0, (size_t)N * 4, stream);
    scatter_reorder_kernel<<<1024, 256, 0, stream>>>(erow, ecol, ef, cs, rowptr, rowcnt, csr_col, csr_ef, E);

    const int gridR = (N + 63) / 64;
    const float* cur = scalar;
    for (int i = 0; i < layers; ++i) {
        const int pb = 6 * i;
        resid_dual_kernel<<<gridR, 512, 0, stream>>>(
            cur,
            wt + (size_t)pb * 32768, resB + (size_t)pb * 256,
            wt + (size_t)(pb + 1) * 32768, resB + (size_t)(pb + 1) * 256,
            Bs16, Cs16, N);
        conv_kernel<<<(N + 3) / 4, 256, 0, stream>>>(
            csr_ef, csr_col, elin16 + (size_t)i * 16 * HD, rowptr, Cs16, Cn, Dc, N);
        chain4_kernel<<<gridR, 512, 0, stream>>>(
            Dc, Bs16,
            wt + (size_t)(pb + 2) * 32768, resB + (size_t)(pb + 2) * 256,
            wt + (size_t)(pb + 3) * 32768, resB + (size_t)(pb + 3) * 256,
            wt + (size_t)(pb + 4) * 32768, resB + (size_t)(pb + 4) * 256,
            wt + (size_t)(pb + 5) * 32768, resB + (size_t)(pb + 5) * 256,
            cur, A, N);
        cur = A;
    }

    hipMemsetAsync(graph, 0, (size_t)G * HD * 4, stream);
    pool_kernel<<<(N + 255) / 256, 256, 0, stream>>>(cur, bidx, graph, N);

    const int q = 6 * layers;
    const int gridG = (G + 63) / 64;
    chain3_kernel<<<gridG, 512, 0, stream>>>(
        graph,
        wt + (size_t)q * 32768, resB + (size_t)q * 256,
        wt + (size_t)(q + 1) * 32768, resB + (size_t)(q + 1) * 256,
        wt + (size_t)(q + 2) * 32768, resB + (size_t)(q + 2) * 256,
        (float*)d_out, G);
}

// Round 7
// 840.854 us; speedup vs baseline: 3.7130x; 1.0543x over previous
//
#include <hip/hip_runtime.h>
#include <hip/hip_bf16.h>
#include <cstdint>
#include <cstddef>

#define HD 128
#define WOFF 16384   // W tile region in LDS (single 16KB data region below it)

typedef __bf16    bf16x8 __attribute__((ext_vector_type(8)));
typedef float     f32x4  __attribute__((ext_vector_type(4)));
typedef _Float16  h2     __attribute__((ext_vector_type(2)));
typedef _Float16  h8     __attribute__((ext_vector_type(8)));

#if defined(__has_builtin)
#if __has_builtin(__builtin_amdgcn_fdot2)
#define HAVE_FDOT2 1
#endif
#endif

__device__ __forceinline__ float fdot2f(h2 a, h2 b, float c) {
#ifdef HAVE_FDOT2
    return __builtin_amdgcn_fdot2(a, b, c, false);
#else
    return c + (float)a[0]*(float)b[0] + (float)a[1]*(float)b[1];
#endif
}

// Swizzled LDS byte offset: row r (256B rows), byte-in-row b. chunk ^= (r&7) kills
// the stride-256B bank conflict on column-slice ds_read_b128.
__device__ __forceinline__ int swz(int r, int byteInRow) {
    int chunk = (byteInRow >> 4) ^ (r & 7);
    return r * 256 + (chunk << 4) + (byteInRow & 15);
}

__device__ __forceinline__ float silu_f(float v) { return v / (1.f + __expf(-v)); }

// ================== 512-thread residual building blocks ==================
// 8 waves: pair (wv>>1) owns rows (wv>>1)*16..+16; sub (wv&1) owns n-tiles nbase=sub*4..+4.
// LDS: [0,16K) data region (x/h/carry share it), [16K,48K) Wbuf.  48KB total -> 3 blocks/CU.

__device__ __forceinline__ void stage_x64(const float* __restrict__ x, char* lds,
                                          int r0, int nrows, int tid) {
    const int q = tid & 15;
    #pragma unroll
    for (int rr = 0; rr < 2; ++rr) {
        const int r  = (tid >> 4) + rr * 32;
        const int gr = r0 + r;
        float4 a = {0,0,0,0}, b = {0,0,0,0};
        if (gr < nrows) {
            const float4* p = (const float4*)(x + (size_t)gr * HD + q * 8);
            a = p[0]; b = p[1];
        }
        bf16x8 v;
        v[0]=(__bf16)a.x; v[1]=(__bf16)a.y; v[2]=(__bf16)a.z; v[3]=(__bf16)a.w;
        v[4]=(__bf16)b.x; v[5]=(__bf16)b.y; v[6]=(__bf16)b.z; v[7]=(__bf16)b.w;
        *(bf16x8*)(lds + swz(r, q * 16)) = v;
    }
}

__device__ __forceinline__ void load_wpref(const __bf16* __restrict__ w, bf16x8 pref[4], int tid) {
    #pragma unroll
    for (int i = 0; i < 4; ++i)
        pref[i] = *(const bf16x8*)(w + (size_t)(i * 512 + tid) * 8);
}
__device__ __forceinline__ void store_wpref(char* lds, const bf16x8 pref[4], int tid) {
    #pragma unroll
    for (int i = 0; i < 4; ++i) {
        const int l = i * 512 + tid;
        *(bf16x8*)(lds + WOFF + swz(l >> 4, (l & 15) * 16)) = pref[i];
    }
}

// acc[ni] = (region @ Wbuf)[rows mrow0.., cols (nbase+ni)*16..] + bias
__device__ __forceinline__ void mm_pass_lds(const char* lds,
                                            const float* __restrict__ bias,
                                            int mrow0, int nbase, int crow, int kgrp, f32x4 acc[4]) {
    bf16x8 afr[4];
    #pragma unroll
    for (int kk = 0; kk < 4; ++kk)
        afr[kk] = *(const bf16x8*)(lds + swz(mrow0 + crow, kk*64 + kgrp*16));
    #pragma unroll
    for (int ni = 0; ni < 4; ++ni) {
        const float bv = bias[(nbase + ni) * 16 + crow];
        f32x4 t = {bv, bv, bv, bv};
        acc[ni] = t;
    }
    #pragma unroll
    for (int ni = 0; ni < 4; ++ni) {
        #pragma unroll
        for (int kk = 0; kk < 4; ++kk) {
            const bf16x8 bfr = *(const bf16x8*)(lds + WOFF + swz((nbase+ni)*16 + crow, kk*64 + kgrp*16));
            acc[ni] = __builtin_amdgcn_mfma_f32_16x16x32_bf16(afr[kk], bfr, acc[ni], 0, 0, 0);
        }
    }
}

// write silu(acc) as bf16 h-tile into the data region (own rows/cols)
__device__ __forceinline__ void write_h64(char* lds, const f32x4 acc[4],
                                          int mrow0, int nbase, int crow, int kgrp) {
    #pragma unroll
    for (int ni = 0; ni < 4; ++ni)
        #pragma unroll
        for (int rg = 0; rg < 4; ++rg)
            *(__bf16*)(lds + swz(mrow0 + kgrp*4 + rg, ((nbase+ni)*16 + crow)*2)) =
                (__bf16)silu_f(acc[ni][rg]);
}

__device__ __forceinline__ void restage64(char* lds, const f32x4 carry[4],
                                          int mrow0, int nbase, int crow, int kgrp) {
    #pragma unroll
    for (int ni = 0; ni < 4; ++ni)
        #pragma unroll
        for (int rg = 0; rg < 4; ++rg)
            *(__bf16*)(lds + swz(mrow0 + kgrp*4 + rg, ((nbase+ni)*16 + crow)*2)) =
                (__bf16)carry[ni][rg];
}

// ---- dual residual: out1 = bf16(x + mlpA(x)), out2 = bf16(x + mlpB(x)) ----
__global__ __launch_bounds__(512) void resid_dual_kernel(
    const float* __restrict__ x,
    const __bf16* __restrict__ wtA, const float* __restrict__ bA,
    const __bf16* __restrict__ wtB, const float* __restrict__ bB,
    __bf16* __restrict__ out1, __bf16* __restrict__ out2, int nrows)
{
    __shared__ char lds[49152];
    const int tid = threadIdx.x, lane = tid & 63, wv = tid >> 6;
    const int crow = lane & 15, kgrp = lane >> 4;
    const int r0 = blockIdx.x * 64;
    const int mrow0 = (wv >> 1) * 16, nbase = (wv & 1) * 4;

    {
        bf16x8 pref[4];
        load_wpref(wtA, pref, tid);
        stage_x64(x, lds, r0, nrows, tid);
        store_wpref(lds, pref, tid);
    }
    f32x4 acc[4], xe[4];
    #pragma unroll
    for (int ni = 0; ni < 4; ++ni)
        #pragma unroll
        for (int rg = 0; rg < 4; ++rg) {
            const int gr = r0 + mrow0 + kgrp*4 + rg;
            xe[ni][rg] = (gr < nrows) ? x[(size_t)gr*HD + (nbase+ni)*16 + crow] : 0.f;
        }
    __syncthreads();

    // A1: h = silu(x @ WA0 + b)
    {
        bf16x8 pref[4];
        load_wpref(wtA + 16384, pref, tid);
        mm_pass_lds(lds, bA, mrow0, nbase, crow, kgrp, acc);
        __syncthreads();                       // all region/Wbuf reads done
        write_h64(lds, acc, mrow0, nbase, crow, kgrp);
        store_wpref(lds, pref, tid);
        __syncthreads();
    }
    // A2: y1 = xe + silu(h @ WA1 + b) -> scattered bf16 stores; then restage x
    {
        bf16x8 pref[4];
        load_wpref(wtB, pref, tid);
        mm_pass_lds(lds, bA + HD, mrow0, nbase, crow, kgrp, acc);
        #pragma unroll
        for (int ni = 0; ni < 4; ++ni)
            #pragma unroll
            for (int rg = 0; rg < 4; ++rg) {
                const int gr = r0 + mrow0 + kgrp*4 + rg;
                if (gr < nrows)
                    out1[(size_t)gr*HD + (nbase+ni)*16 + crow] =
                        (__bf16)(xe[ni][rg] + silu_f(acc[ni][rg]));
            }
        __syncthreads();
        restage64(lds, xe, mrow0, nbase, crow, kgrp);   // region <- x again
        store_wpref(lds, pref, tid);
        __syncthreads();
    }
    // B1
    {
        bf16x8 pref[4];
        load_wpref(wtB + 16384, pref, tid);
        mm_pass_lds(lds, bB, mrow0, nbase, crow, kgrp, acc);
        __syncthreads();
        write_h64(lds, acc, mrow0, nbase, crow, kgrp);
        store_wpref(lds, pref, tid);
        __syncthreads();
    }
    // B2
    mm_pass_lds(lds, bB + HD, mrow0, nbase, crow, kgrp, acc);
    #pragma unroll
    for (int ni = 0; ni < 4; ++ni)
        #pragma unroll
        for (int rg = 0; rg < 4; ++rg) {
            const int gr = r0 + mrow0 + kgrp*4 + rg;
            if (gr < nrows)
                out2[(size_t)gr*HD + (nbase+ni)*16 + crow] =
                    (__bf16)(xe[ni][rg] + silu_f(acc[ni][rg]));
        }
}

// one residual sub-block on the shared region: carry += silu(mlp(region)); region <- carry
// (wNext0 staged into Wbuf for the following sub-block)
__device__ __forceinline__ void sub_block(char* lds, const __bf16* __restrict__ w1,
                                          const __bf16* __restrict__ wNext0,
                                          const float* __restrict__ bias,
                                          int tid, int mrow0, int nbase, int crow, int kgrp,
                                          f32x4 carry[4], f32x4 acc[4]) {
    {
        bf16x8 pref[4];
        load_wpref(w1, pref, tid);
        mm_pass_lds(lds, bias, mrow0, nbase, crow, kgrp, acc);
        __syncthreads();
        write_h64(lds, acc, mrow0, nbase, crow, kgrp);
        store_wpref(lds, pref, tid);
        __syncthreads();
    }
    {
        bf16x8 pref[4];
        load_wpref(wNext0, pref, tid);
        mm_pass_lds(lds, bias + HD, mrow0, nbase, crow, kgrp, acc);
        #pragma unroll
        for (int ni = 0; ni < 4; ++ni)
            #pragma unroll
            for (int rg = 0; rg < 4; ++rg) carry[ni][rg] += silu_f(acc[ni][rg]);
        __syncthreads();
        restage64(lds, carry, mrow0, nbase, crow, kgrp);
        store_wpref(lds, pref, tid);
        __syncthreads();
    }
}

// ---- fused 4-block chain: y = post + R_D(R_C(mid ⊙ R_B(R_A(x)))), f32 carry in regs ----
__global__ __launch_bounds__(512) void chain4_kernel(
    const float* __restrict__ x, const __bf16* __restrict__ mid,
    const __bf16* __restrict__ wA, const float* __restrict__ bA,
    const __bf16* __restrict__ wB, const float* __restrict__ bB,
    const __bf16* __restrict__ wC, const float* __restrict__ bC,
    const __bf16* __restrict__ wD, const float* __restrict__ bD,
    const float* __restrict__ post, float* __restrict__ y, int nrows)
{
    __shared__ char lds[49152];
    const int tid = threadIdx.x, lane = tid & 63, wv = tid >> 6;
    const int crow = lane & 15, kgrp = lane >> 4;
    const int r0 = blockIdx.x * 64;
    const int mrow0 = (wv >> 1) * 16, nbase = (wv & 1) * 4;

    {
        bf16x8 pref[4];
        load_wpref(wA, pref, tid);
        stage_x64(x, lds, r0, nrows, tid);
        store_wpref(lds, pref, tid);
    }
    f32x4 carry[4], acc[4];
    #pragma unroll
    for (int ni = 0; ni < 4; ++ni)
        #pragma unroll
        for (int rg = 0; rg < 4; ++rg) {
            const int gr = r0 + mrow0 + kgrp*4 + rg;
            carry[ni][rg] = (gr < nrows) ? x[(size_t)gr*HD + (nbase+ni)*16 + crow] : 0.f;
        }
    __syncthreads();

    // SB A
    sub_block(lds, wA + 16384, wB, bA, tid, mrow0, nbase, crow, kgrp, carry, acc);
    // SB B with mid-multiply folded into the carry restage: redo restage after multiply
    {
        bf16x8 pref[4];
        load_wpref(wB + 16384, pref, tid);
        mm_pass_lds(lds, bB, mrow0, nbase, crow, kgrp, acc);
        __syncthreads();
        write_h64(lds, acc, mrow0, nbase, crow, kgrp);
        store_wpref(lds, pref, tid);
        __syncthreads();
    }
    {
        bf16x8 pref[4];
        load_wpref(wC, pref, tid);
        mm_pass_lds(lds, bB + HD, mrow0, nbase, crow, kgrp, acc);
        #pragma unroll
        for (int ni = 0; ni < 4; ++ni)
            #pragma unroll
            for (int rg = 0; rg < 4; ++rg) {
                const int gr = r0 + mrow0 + kgrp*4 + rg;
                const float m = (gr < nrows) ? (float)mid[(size_t)gr*HD + (nbase+ni)*16 + crow] : 0.f;
                carry[ni][rg] = (carry[ni][rg] + silu_f(acc[ni][rg])) * m;
            }
        __syncthreads();
        restage64(lds, carry, mrow0, nbase, crow, kgrp);
        store_wpref(lds, pref, tid);
        __syncthreads();
    }
    // SB C
    sub_block(lds, wC + 16384, wD, bC, tid, mrow0, nbase, crow, kgrp, carry, acc);
    // SB D
    {
        bf16x8 pref[4];
        load_wpref(wD + 16384, pref, tid);
        mm_pass_lds(lds, bD, mrow0, nbase, crow, kgrp, acc);
        __syncthreads();
        write_h64(lds, acc, mrow0, nbase, crow, kgrp);
        store_wpref(lds, pref, tid);
        __syncthreads();
    }
    mm_pass_lds(lds, bD + HD, mrow0, nbase, crow, kgrp, acc);
    #pragma unroll
    for (int ni = 0; ni < 4; ++ni)
        #pragma unroll
        for (int rg = 0; rg < 4; ++rg) {
            const int gr = r0 + mrow0 + kgrp*4 + rg;
            if (gr < nrows) {
                const int cc = (nbase+ni)*16 + crow;
                y[(size_t)gr*HD + cc] = carry[ni][rg] + silu_f(acc[ni][rg]) + post[(size_t)gr*HD + cc];
            }
        }
}

// ---- fused 3-block graph chain: out = R_C(R_B(R_A(x))) ----
__global__ __launch_bounds__(512) void chain3_kernel(
    const float* __restrict__ x,
    const __bf16* __restrict__ wA, const float* __restrict__ bA,
    const __bf16* __restrict__ wB, const float* __restrict__ bB,
    const __bf16* __restrict__ wC, const float* __restrict__ bC,
    float* __restrict__ y, int nrows)
{
    __shared__ char lds[49152];
    const int tid = threadIdx.x, lane = tid & 63, wv = tid >> 6;
    const int crow = lane & 15, kgrp = lane >> 4;
    const int r0 = blockIdx.x * 64;
    const int mrow0 = (wv >> 1) * 16, nbase = (wv & 1) * 4;

    {
        bf16x8 pref[4];
        load_wpref(wA, pref, tid);
        stage_x64(x, lds, r0, nrows, tid);
        store_wpref(lds, pref, tid);
    }
    f32x4 carry[4], acc[4];
    #pragma unroll
    for (int ni = 0; ni < 4; ++ni)
        #pragma unroll
        for (int rg = 0; rg < 4; ++rg) {
            const int gr = r0 + mrow0 + kgrp*4 + rg;
            carry[ni][rg] = (gr < nrows) ? x[(size_t)gr*HD + (nbase+ni)*16 + crow] : 0.f;
        }
    __syncthreads();

    sub_block(lds, wA + 16384, wB, bA, tid, mrow0, nbase, crow, kgrp, carry, acc);
    sub_block(lds, wB + 16384, wC, bB, tid, mrow0, nbase, crow, kgrp, carry, acc);
    {
        bf16x8 pref[4];
        load_wpref(wC + 16384, pref, tid);
        mm_pass_lds(lds, bC, mrow0, nbase, crow, kgrp, acc);
        __syncthreads();
        write_h64(lds, acc, mrow0, nbase, crow, kgrp);
        store_wpref(lds, pref, tid);
        __syncthreads();
    }
    mm_pass_lds(lds, bC + HD, mrow0, nbase, crow, kgrp, acc);
    #pragma unroll
    for (int ni = 0; ni < 4; ++ni)
        #pragma unroll
        for (int rg = 0; rg < 4; ++rg) {
            const int gr = r0 + mrow0 + kgrp*4 + rg;
            if (gr < nrows)
                y[(size_t)gr*HD + (nbase+ni)*16 + crow] = carry[ni][rg] + silu_f(acc[ni][rg]);
        }
}

// ---- CSR build ----
__global__ __launch_bounds__(256) void hist_kernel(const int* __restrict__ erow, int* __restrict__ cnt, int E) {
    int i = blockIdx.x * blockDim.x + threadIdx.x;
    const int stride = gridDim.x * blockDim.x;
    for (; i < E; i += stride) atomicAdd(&cnt[erow[i]], 1);
}

__global__ __launch_bounds__(256) void scan1_kernel(const int* __restrict__ cnt, int* __restrict__ part, int n) {
    __shared__ int red[256];
    const int base = blockIdx.x * 1024;
    int s = 0;
    for (int i = threadIdx.x; i < 1024; i += 256) {
        const int idx = base + i;
        s += (idx < n) ? cnt[idx] : 0;
    }
    red[threadIdx.x] = s; __syncthreads();
    for (int o = 128; o > 0; o >>= 1) {
        if (threadIdx.x < o) red[threadIdx.x] += red[threadIdx.x + o];
        __syncthreads();
    }
    if (threadIdx.x == 0) part[blockIdx.x] = red[0];
}

__global__ __launch_bounds__(256) void scan2_kernel(int* __restrict__ part, int nb,
                                                    int* __restrict__ rowptr, int n) {
    __shared__ int sh[257];
    const int tid = threadIdx.x;
    int a[4]; int s = 0;
    #pragma unroll
    for (int q = 0; q < 4; ++q) {
        const int i = tid*4 + q;
        a[q] = (i < nb) ? part[i] : 0;
        s += a[q];
    }
    sh[tid + 1] = s; __syncthreads();
    if (tid == 0) {
        sh[0] = 0;
        int run = 0;
        for (int i = 1; i <= 256; ++i) { run += sh[i]; sh[i] = run; }
    }
    __syncthreads();
    int off = sh[tid];
    #pragma unroll
    for (int q = 0; q < 4; ++q) {
        const int i = tid*4 + q;
        if (i < nb) part[i] = off;
        off += a[q];
    }
    if (tid == 255) rowptr[n] = off;
}

__global__ __launch_bounds__(256) void scan3_kernel(const int* __restrict__ cnt, const int* __restrict__ part,
                                                    int* __restrict__ rowptr, int n) {
    __shared__ int sc[257];
    const int base = blockIdx.x * 1024;
    const int i0 = base + threadIdx.x * 4;
    int v[4]; int s = 0;
    #pragma unroll
    for (int q = 0; q < 4; ++q) {
        const int idx = i0 + q;
        v[q] = (idx < n) ? cnt[idx] : 0;
        s += v[q];
    }
    sc[threadIdx.x + 1] = s; __syncthreads();
    if (threadIdx.x == 0) {
        int run = 0;
        for (int i = 0; i < 256; ++i) { const int t = sc[i + 1]; sc[i + 1] = run; run += t; }
    }
    __syncthreads();
    int off = part[blockIdx.x] + sc[threadIdx.x + 1];
    #pragma unroll
    for (int q = 0; q < 4; ++q) {
        const int idx = i0 + q;
        if (idx < n) rowptr[idx] = off;
        off += v[q];
    }
}

// scatter + reorder fused: csr_col[p] = ecol[i], csr_ef[p] = fp16(ef[i] * cs[i])
__global__ __launch_bounds__(256) void scatter_reorder_kernel(
    const int* __restrict__ erow, const int* __restrict__ ecol,
    const float* __restrict__ ef, const float* __restrict__ cs,
    const int* __restrict__ rowptr, int* __restrict__ cursor,
    int* __restrict__ csr_col, _Float16* __restrict__ csr_ef, int E)
{
    int i = blockIdx.x * blockDim.x + threadIdx.x;
    const int stride = gridDim.x * blockDim.x;
    for (; i < E; i += stride) {
        const int r = erow[i];
        const int p = rowptr[r] + atomicAdd(&cursor[r], 1);
        csr_col[p] = ecol[i];
        const float c = cs[i];
        const float4* ep = (const float4*)(ef + (size_t)i * 16);
        const float4 e0 = ep[0], e1 = ep[1], e2 = ep[2], e3 = ep[3];
        h8 v0, v1;
        v0[0]=(_Float16)(e0.x*c); v0[1]=(_Float16)(e0.y*c); v0[2]=(_Float16)(e0.z*c); v0[3]=(_Float16)(e0.w*c);
        v0[4]=(_Float16)(e1.x*c); v0[5]=(_Float16)(e1.y*c); v0[6]=(_Float16)(e1.z*c); v0[7]=(_Float16)(e1.w*c);
        v1[0]=(_Float16)(e2.x*c); v1[1]=(_Float16)(e2.y*c); v1[2]=(_Float16)(e2.z*c); v1[3]=(_Float16)(e2.w*c);
        v1[4]=(_Float16)(e3.x*c); v1[5]=(_Float16)(e3.y*c); v1[6]=(_Float16)(e3.z*c); v1[7]=(_Float16)(e3.w*c);
        h8* dst = (h8*)(csr_ef + (size_t)p * 16);
        dst[0] = v0; dst[1] = v1;
    }
}

// elin f32 [16][128] -> fp16 (per layer)
__global__ __launch_bounds__(256) void elin16_kernel(const float* __restrict__ elin,
                                                     _Float16* __restrict__ out, int total) {
    const int i = blockIdx.x * 256 + threadIdx.x;
    if (i < total) out[i] = (_Float16)elin[i];
}

__device__ __forceinline__ float bfu_lo(uint32_t u) { return __uint_as_float(u << 16); }
__device__ __forceinline__ float bfu_hi(uint32_t u) { return __uint_as_float(u & 0xffff0000u); }

__device__ __forceinline__ void edge_dot(const h8 a0, const h8 a1,
                                         const h2 w0[8], const h2 w1[8],
                                         float& f0, float& f1) {
    #pragma unroll
    for (int kk = 0; kk < 4; ++kk) {
        h2 p = {a0[2*kk], a0[2*kk+1]};
        f0 = fdot2f(p, w0[kk], f0);
        f1 = fdot2f(p, w1[kk], f1);
    }
    #pragma unroll
    for (int kk = 0; kk < 4; ++kk) {
        h2 p = {a1[2*kk], a1[2*kk+1]};
        f0 = fdot2f(p, w0[4+kk], f0);
        f1 = fdot2f(p, w1[4+kk], f1);
    }
}

// ---- CSR gather conv, wave-per-node: lane handles cols (2l, 2l+1); unroll-8 gathers ----
__global__ __launch_bounds__(256) void conv_kernel(
    const _Float16* __restrict__ csr_ef, const int* __restrict__ csr_col,
    const _Float16* __restrict__ elin16, const int* __restrict__ rowptr,
    const __bf16* __restrict__ sdst, const float* __restrict__ Cn,
    float* __restrict__ conv, int nnodes)
{
    const int wv   = __builtin_amdgcn_readfirstlane(threadIdx.x >> 6);
    const int lane = threadIdx.x & 63;
    const int v = blockIdx.x * 4 + wv;
    if (v >= nnodes) return;
    const int j0 = lane * 2;

    h2 w0[8], w1[8];
    #pragma unroll
    for (int kk = 0; kk < 8; ++kk) {
        w0[kk][0] = elin16[(2*kk)   * HD + j0];
        w0[kk][1] = elin16[(2*kk+1) * HD + j0];
        w1[kk][0] = elin16[(2*kk)   * HD + j0 + 1];
        w1[kk][1] = elin16[(2*kk+1) * HD + j0 + 1];
    }

    const uint16_t* sd = (const uint16_t*)sdst;
    const int beg = rowptr[v], end = rowptr[v + 1];
    float acc0 = 0.f, acc1 = 0.f;
    int t = beg;
    for (; t + 8 <= end; t += 8) {
        int c[8];
        #pragma unroll
        for (int q = 0; q < 8; ++q) c[q] = csr_col[t + q];
        uint32_t u[8];
        #pragma unroll
        for (int q = 0; q < 8; ++q)
            u[q] = *(const uint32_t*)(sd + (size_t)c[q] * HD + j0);
        #pragma unroll
        for (int q = 0; q < 8; ++q) {
            const h8* ep = (const h8*)(csr_ef + (size_t)(t + q) * 16);
            const h8 a0 = ep[0], a1 = ep[1];
            float f0 = 0.f, f1 = 0.f;
            edge_dot(a0, a1, w0, w1, f0, f1);
            acc0 = fmaf(bfu_lo(u[q]), f0, acc0);
            acc1 = fmaf(bfu_hi(u[q]), f1, acc1);
        }
    }
    for (; t + 2 <= end; t += 2) {
        int c[2];
        c[0] = csr_col[t]; c[1] = csr_col[t + 1];
        uint32_t u[2];
        u[0] = *(const uint32_t*)(sd + (size_t)c[0] * HD + j0);
        u[1] = *(const uint32_t*)(sd + (size_t)c[1] * HD + j0);
        #pragma unroll
        for (int q = 0; q < 2; ++q) {
            const h8* ep = (const h8*)(csr_ef + (size_t)(t + q) * 16);
            const h8 a0 = ep[0], a1 = ep[1];
            float f0 = 0.f, f1 = 0.f;
            edge_dot(a0, a1, w0, w1, f0, f1);
            acc0 = fmaf(bfu_lo(u[q]), f0, acc0);
            acc1 = fmaf(bfu_hi(u[q]), f1, acc1);
        }
    }
    if (t < end) {
        const int c = csr_col[t];
        const uint32_t u = *(const uint32_t*)(sd + (size_t)c * HD + j0);
        const h8* ep = (const h8*)(csr_ef + (size_t)t * 16);
        const h8 a0 = ep[0], a1 = ep[1];
        float f0 = 0.f, f1 = 0.f;
        edge_dot(a0, a1, w0, w1, f0, f1);
        acc0 = fmaf(bfu_lo(u), f0, acc0);
        acc1 = fmaf(bfu_hi(u), f1, acc1);
    }
    const float cn = Cn[v];
    float2 out = {acc0 * cn, acc1 * cn};
    *(float2*)(conv + (size_t)v * HD + j0) = out;
}

// sorted segment-sum pooling: 256 thr = 8 row-slots x 32 col-quads; per-thread running acc
__global__ __launch_bounds__(256) void pool_kernel(
    const float* __restrict__ s, const int* __restrict__ bidx,
    float* __restrict__ g, int n)
{
    const int slot = threadIdx.x >> 5;
    const int jc   = (threadIdx.x & 31) * 4;
    const int base = blockIdx.x * 256;
    if (base >= n) return;
    const int end = (base + 256 < n) ? base + 256 : n;
    float4 acc = {0,0,0,0};
    int cur = -1;
    for (int i = base + slot; i < end; i += 8) {
        const int b = bidx[i];
        if (b != cur) {
            if (cur >= 0) {
                atomicAdd(g + (size_t)cur*HD + jc + 0, acc.x);
                atomicAdd(g + (size_t)cur*HD + jc + 1, acc.y);
                atomicAdd(g + (size_t)cur*HD + jc + 2, acc.z);
                atomicAdd(g + (size_t)cur*HD + jc + 3, acc.w);
            }
            acc = {0,0,0,0};
            cur = b;
        }
        const float4 v = *(const float4*)(s + (size_t)i*HD + jc);
        acc.x += v.x; acc.y += v.y; acc.z += v.z; acc.w += v.w;
    }
    if (cur >= 0) {
        atomicAdd(g + (size_t)cur*HD + jc + 0, acc.x);
        atomicAdd(g + (size_t)cur*HD + jc + 1, acc.y);
        atomicAdd(g + (size_t)cur*HD + jc + 2, acc.z);
        atomicAdd(g + (size_t)cur*HD + jc + 3, acc.w);
    }
}

// wt[mat][j][k] = (bf16) W[mat][k][j]
__global__ __launch_bounds__(256) void convw_kernel(const float* __restrict__ W, __bf16* __restrict__ wt, int total) {
    const int idx = blockIdx.x * 256 + threadIdx.x;
    if (idx >= total) return;
    const int mat = idx >> 14;
    const int rem = idx & 16383;
    const int jj = rem >> 7, kk = rem & 127;
    wt[idx] = (__bf16)W[(size_t)mat * 16384 + kk * HD + jj];
}

extern "C" void kernel_launch(void* const* d_in, const int* in_sizes, int n_in,
                              void* d_out, int out_size, void* d_ws, size_t ws_size,
                              hipStream_t stream) {
    const float* scalar = (const float*)d_in[0];
    const float* ef     = (const float*)d_in[1];
    const int*   eidx   = (const int*)  d_in[2];
    const float* Cn     = (const float*)d_in[3];
    const float* cs     = (const float*)d_in[4];
    const int*   bidx   = (const int*)  d_in[5];
    const float* resW   = (const float*)d_in[6];
    const float* resB   = (const float*)d_in[7];
    const float* elin   = (const float*)d_in[8];

    const int N      = in_sizes[0] / HD;
    const int E      = in_sizes[1] / 16;
    const int n_res  = in_sizes[7] / (2 * HD);
    const int layers = (n_res - 3) / 6;
    const int G      = out_size / HD;
    const size_t nfeat = (size_t)N * HD;

    char* p = (char*)d_ws;
    auto alloc = [&](size_t bytes) { char* q = p; p += (bytes + 255) & ~(size_t)255; return q; };
    float*    A      = (float*)alloc(nfeat * 4);
    float*    Dc     = (float*)alloc(nfeat * 4);
    __bf16*   Bs16   = (__bf16*)alloc(nfeat * 2);
    __bf16*   Cs16   = (__bf16*)alloc(nfeat * 2);
    __bf16*   wt     = (__bf16*)alloc((size_t)n_res * 2 * 16384 * 2);
    float*    graph  = (float*)alloc((size_t)G * HD * 4);
    int*      rowptr = (int*)alloc((size_t)(N + 1) * 4);
    int*      rowcnt = (int*)alloc((size_t)N * 4);
    int*      csr_col= (int*)alloc((size_t)E * 4);
    _Float16* csr_ef = (_Float16*)alloc((size_t)E * 16 * 2);
    _Float16* elin16 = (_Float16*)alloc((size_t)layers * 16 * HD * 2);
    int*      part   = (int*)alloc(1024 * 4);

    const int* erow = eidx;
    const int* ecol = eidx + E;

    const int totW = n_res * 2 * 16384;
    convw_kernel<<<(totW + 255) / 256, 256, 0, stream>>>(resW, wt, totW);
    const int totE = layers * 16 * HD;
    elin16_kernel<<<(totE + 255) / 256, 256, 0, stream>>>(elin, elin16, totE);

    const int nchunks = (N + 1023) / 1024;
    hipMemsetAsync(rowcnt, 0, (size_t)N * 4, stream);
    hist_kernel<<<1024, 256, 0, stream>>>(erow, rowcnt, E);
    scan1_kernel<<<nchunks, 256, 0, stream>>>(rowcnt, part, N);
    scan2_kernel<<<1, 256, 0, stream>>>(part, nchunks, rowptr, N);
    scan3_kernel<<<nchunks, 256, 0, stream>>>(rowcnt, part, rowptr, N);
    hipMemsetAsync(rowcnt, 0, (size_t)N * 4, stream);
    scatter_reorder_kernel<<<1024, 256, 0, stream>>>(erow, ecol, ef, cs, rowptr, rowcnt, csr_col, csr_ef, E);

    const int gridR = (N + 63) / 64;
    const float* cur = scalar;
    for (int i = 0; i < layers; ++i) {
        const int pb = 6 * i;
        resid_dual_kernel<<<gridR, 512, 0, stream>>>(
            cur,
            wt + (size_t)pb * 32768, resB + (size_t)pb * 256,
            wt + (size_t)(pb + 1) * 32768, resB + (size_t)(pb + 1) * 256,
            Bs16, Cs16, N);
        conv_kernel<<<(N + 3) / 4, 256, 0, stream>>>(
            csr_ef, csr_col, elin16 + (size_t)i * 16 * HD, rowptr, Cs16, Cn, Dc, N);
        chain4_kernel<<<gridR, 512, 0, stream>>>(
            Dc, Bs16,
            wt + (size_t)(pb + 2) * 32768, resB + (size_t)(pb + 2) * 256,
            wt + (size_t)(pb + 3) * 32768, resB + (size_t)(pb + 3) * 256,
            wt + (size_t)(pb + 4) * 32768, resB + (size_t)(pb + 4) * 256,
            wt + (size_t)(pb + 5) * 32768, resB + (size_t)(pb + 5) * 256,
            cur, A, N);
        cur = A;
    }

    hipMemsetAsync(graph, 0, (size_t)G * HD * 4, stream);
    pool_kernel<<<(N + 255) / 256, 256, 0, stream>>>(cur, bidx, graph, N);

    const int q = 6 * layers;
    const int gridG = (G + 63) / 64;
    chain3_kernel<<<gridG, 512, 0, stream>>>(
        graph,
        wt + (size_t)q * 32768, resB + (size_t)q * 256,
        wt + (size_t)(q + 1) * 32768, resB + (size_t)(q + 1) * 256,
        wt + (size_t)(q + 2) * 32768, resB + (size_t)(q + 2) * 256,
        (float*)d_out, G);
}